// Round 4
// baseline (1395.401 us; speedup 1.0000x reference)
//
#include <hip/hip_runtime.h>
#include <math.h>

#define SEQ 2048
#define DMODEL 1024
#define NHEADS 16
#define DHEAD 64

typedef long long i64;
typedef unsigned short u16;
typedef __attribute__((ext_vector_type(4))) float f32x4;
typedef __attribute__((ext_vector_type(8))) short bf16x8;

#define IN_E  2097152   // 2048*1024
#define W_E   1048576   // 1024*1024
#define HEAD_E 131072   // 2048*64

// LDS bank-conflict swizzle for u16 staging tiles (rows of 32 u16 = 64B):
// XOR u16-index bits [3:5] with key bits [6:8] ((row>>1)&7). Involution.
// Spreads a 16-lane ds_read_b128 fragment group across all 32 banks.
#define SWZ(idx) ((idx) ^ ((((idx) >> 6) & 7) << 3))

// ---------------------------------------------------------------------------
// bf16 split helpers
// ---------------------------------------------------------------------------
__device__ inline u16 f2bf(float x) {                // RNE
    union { float f; unsigned u; } v; v.f = x;
    unsigned r = v.u + 0x7FFF + ((v.u >> 16) & 1);
    return (u16)(r >> 16);
}
__device__ inline float bf2f(u16 h) {
    union { unsigned u; float f; } v; v.u = ((unsigned)h) << 16;
    return v.f;
}

__device__ inline void gload16(const void* g, void* l) {
    __builtin_amdgcn_global_load_lds(
        (const __attribute__((address_space(1))) unsigned int*)g,
        (__attribute__((address_space(3))) unsigned int*)l, 16, 0, 0);
}

// ---------------------------------------------------------------------------
// Split 8 f32 arrays into bf16 hi/lo. z = array id, float4 per thread.
// ---------------------------------------------------------------------------
struct SplitArgs {
    const float* src[8];
    u16* dh[8];
    u16* dl[8];
    int n4[8];
};
__global__ __launch_bounds__(256)
void split_all(SplitArgs a)
{
    const int z = blockIdx.y;
    const int i = blockIdx.x * 256 + threadIdx.x;
    if (i >= a.n4[z]) return;
    const float4 x = ((const float4*)a.src[z])[i];
    u16 h0 = f2bf(x.x), h1 = f2bf(x.y), h2 = f2bf(x.z), h3 = f2bf(x.w);
    u16 l0 = f2bf(x.x - bf2f(h0)), l1 = f2bf(x.y - bf2f(h1));
    u16 l2 = f2bf(x.z - bf2f(h2)), l3 = f2bf(x.w - bf2f(h3));
    uint2 hh; hh.x = (unsigned)h0 | ((unsigned)h1 << 16); hh.y = (unsigned)h2 | ((unsigned)h3 << 16);
    uint2 ll; ll.x = (unsigned)l0 | ((unsigned)l1 << 16); ll.y = (unsigned)l2 | ((unsigned)l3 << 16);
    ((uint2*)a.dh[z])[i] = hh;
    ((uint2*)a.dl[z])[i] = ll;
}

// ---------------------------------------------------------------------------
// rel_enc computed + split directly
// ---------------------------------------------------------------------------
__global__ __launch_bounds__(256)
void posenc_split(u16* __restrict__ dh, u16* __restrict__ dl)
{
    const int idx = blockIdx.x * 256 + threadIdx.x;
    const int f = idx >> 10;
    const int i = idx & 1023;
    const float P = (float)(SEQ - 1 - f);
    const float ex = (float)(i & ~1) * (1.f / 1024.f);
    const float dv = powf(10000.f, -ex);
    const float ang = P * dv;
    const float val = (i & 1) ? cosf(ang) : sinf(ang);
    const u16 hb = f2bf(val);
    dh[idx] = hb;
    dl[idx] = f2bf(val - bf2f(hb));
}

// ---------------------------------------------------------------------------
// Split-3 bf16 MFMA TN GEMM, 128x128 tile, BK=32.  (projections + final GELU)
// ---------------------------------------------------------------------------
struct TNArgs {
    const u16 *Ah, *Al, *Bh, *Bl;
    i64 sAz, sBz;
    float* Cf; i64 sCz; int ldc;
    u16 *O1h, *O1l, *O2h, *O2l;
    const float *b1, *b2;
    int K, mode;
};

__global__ __launch_bounds__(256)
void mfma_tn128(TNArgs p)
{
    __shared__ __align__(16) u16 Ash[128 * 32];
    __shared__ __align__(16) u16 Asl[128 * 32];
    __shared__ __align__(16) u16 Bsh[128 * 32];
    __shared__ __align__(16) u16 Bsl[128 * 32];
    const int tid = threadIdx.x, wave = tid >> 6, lane = tid & 63;
    const int z = blockIdx.z;
    const i64 m0 = (i64)blockIdx.y * 128, n0 = (i64)blockIdx.x * 128;
    const int K = p.K;
    const u16* Abh = p.Ah + (i64)z * p.sAz;
    const u16* Abl = p.Al + (i64)z * p.sAz;
    const u16* Bbh = p.Bh + (i64)z * p.sBz;
    const u16* Bbl = p.Bl + (i64)z * p.sBz;
    const int r0 = tid >> 2, kc = (tid & 3) * 8;
    const int r1 = r0 + 64;
    u16* dA0 = &Ash[wave * 512];
    u16* dA1 = &Ash[2048 + wave * 512];
    u16* dA0l = &Asl[wave * 512];
    u16* dA1l = &Asl[2048 + wave * 512];
    u16* dB0 = &Bsh[wave * 512];
    u16* dB1 = &Bsh[2048 + wave * 512];
    u16* dB0l = &Bsl[wave * 512];
    u16* dB1l = &Bsl[2048 + wave * 512];
    const int wm = (wave >> 1) * 64, wn = (wave & 1) * 64;
    f32x4 acc[4][4] = {};

    for (int k0 = 0; k0 < K; k0 += 32) {
        __syncthreads();
        const i64 ga0 = (m0 + r0) * K + k0 + kc;
        const i64 ga1 = (m0 + r1) * K + k0 + kc;
        const i64 gb0 = (n0 + r0) * K + k0 + kc;
        const i64 gb1 = (n0 + r1) * K + k0 + kc;
        gload16(Abh + ga0, dA0);  gload16(Abh + ga1, dA1);
        gload16(Abl + ga0, dA0l); gload16(Abl + ga1, dA1l);
        gload16(Bbh + gb0, dB0);  gload16(Bbh + gb1, dB1);
        gload16(Bbl + gb0, dB0l); gload16(Bbl + gb1, dB1l);
        __syncthreads();
        const int fr = lane & 15, fk = (lane >> 4) * 8;
        bf16x8 fah[4], fal[4], fbh[4], fbl[4];
#pragma unroll
        for (int t = 0; t < 4; ++t) {
            fah[t] = *(const bf16x8*)&Ash[(wm + t * 16 + fr) * 32 + fk];
            fal[t] = *(const bf16x8*)&Asl[(wm + t * 16 + fr) * 32 + fk];
            fbh[t] = *(const bf16x8*)&Bsh[(wn + t * 16 + fr) * 32 + fk];
            fbl[t] = *(const bf16x8*)&Bsl[(wn + t * 16 + fr) * 32 + fk];
        }
#pragma unroll
        for (int mi = 0; mi < 4; ++mi)
#pragma unroll
            for (int ni = 0; ni < 4; ++ni) {
                acc[mi][ni] = __builtin_amdgcn_mfma_f32_16x16x32_bf16(fah[mi], fbh[ni], acc[mi][ni], 0, 0, 0);
                acc[mi][ni] = __builtin_amdgcn_mfma_f32_16x16x32_bf16(fah[mi], fbl[ni], acc[mi][ni], 0, 0, 0);
                acc[mi][ni] = __builtin_amdgcn_mfma_f32_16x16x32_bf16(fal[mi], fbh[ni], acc[mi][ni], 0, 0, 0);
            }
    }

    const int fr = lane & 15, fq = (lane >> 4) * 4;
    if (p.mode == 0) {
        float* C = p.Cf + (i64)z * p.sCz;
#pragma unroll
        for (int mi = 0; mi < 4; ++mi)
#pragma unroll
            for (int e = 0; e < 4; ++e) {
                const i64 row = m0 + wm + mi * 16 + fq + e;
#pragma unroll
                for (int ni = 0; ni < 4; ++ni)
                    C[row * p.ldc + n0 + wn + ni * 16 + fr] = acc[mi][ni][e];
            }
    } else if (p.mode == 1) {
        const i64 obase = (i64)z * IN_E;
#pragma unroll
        for (int mi = 0; mi < 4; ++mi)
#pragma unroll
            for (int e = 0; e < 4; ++e) {
                const i64 m = m0 + wm + mi * 16 + fq + e;
#pragma unroll
                for (int ni = 0; ni < 4; ++ni) {
                    const int c = (int)n0 + wn + ni * 16 + fr;
                    const int h = c >> 6, d = c & 63;
                    const i64 off = ((i64)h * SEQ + m) * DHEAD + d;
                    float v = acc[mi][ni][e];
                    if (z == 0) v += p.b1[c];
                    const u16 hb = f2bf(v);
                    const u16 lb = f2bf(v - bf2f(hb));
                    p.O1h[obase + off] = hb;
                    p.O1l[obase + off] = lb;
                    if (z == 0) {
                        const float v2 = acc[mi][ni][e] + p.b2[c];
                        const u16 hb2 = f2bf(v2);
                        const u16 lb2 = f2bf(v2 - bf2f(hb2));
                        p.O2h[off] = hb2;
                        p.O2l[off] = lb2;
                    }
                }
            }
    } else { // mode 2: exact GELU
        float* C = p.Cf;
#pragma unroll
        for (int mi = 0; mi < 4; ++mi)
#pragma unroll
            for (int e = 0; e < 4; ++e) {
                const i64 row = m0 + wm + mi * 16 + fq + e;
#pragma unroll
                for (int ni = 0; ni < 4; ++ni) {
                    const float x = acc[mi][ni][e];
                    C[row * p.ldc + n0 + wn + ni * 16 + fr] =
                        0.5f * x * (1.f + erff(x * 0.70710678118654752f));
                }
            }
    }
}

// ---------------------------------------------------------------------------
// Fused score kernel: S = (q+u)kk^T + shift((q+v)rr^T), raw (unscaled) f32.
// B_D[i][j] depends only on (i, d=i-j):
//   d>=0 : Ghat[i  ][2047-d];  d==-1: 0;  d<=-2: Ghat[i+1][-d-2]
// Band chunks of 128x64 through bandc, which OVERLAYS the staging LDS
// (disjoint in time) -> ~34.5KB LDS -> 4 blocks/CU.
// Staging uses SWZ bank-conflict swizzle: linear LDS dest (global_load_lds),
// pre-swizzled per-lane GLOBAL source, swizzled ds_read on the read side.
// ---------------------------------------------------------------------------
struct ScoreArgs {
    const u16 *quh, *qul, *kkh, *kkl, *qvh, *qvl, *rrh, *rrl;
    float* Cf;
};

__global__ __launch_bounds__(256, 4)
void mfma_score(ScoreArgs p)
{
    __shared__ __align__(16) u16 SMEMU[16896];        // 33792 B union
    u16* Ash = SMEMU;                                 // 128*32
    u16* Asl = SMEMU + 4096;
    u16* Bsh = SMEMU + 8192;
    u16* Bsl = SMEMU + 12288;
    float* bandc = (float*)SMEMU;                     // 128*66 overlay
    __shared__ float fixrow[128];
    __shared__ float qvrow[64];

    const int tid = threadIdx.x, wave = tid >> 6, lane = tid & 63;
    const int z = blockIdx.z;
    const int m0 = blockIdx.y * 128, n0 = blockIdx.x * 128;
    const int D0 = m0 - n0;
    const u16* quh = p.quh + (i64)z * HEAD_E;
    const u16* qul = p.qul + (i64)z * HEAD_E;
    const u16* kkh = p.kkh + (i64)z * HEAD_E;
    const u16* kkl = p.kkl + (i64)z * HEAD_E;
    const u16* qvh = p.qvh + (i64)z * HEAD_E;
    const u16* qvl = p.qvl + (i64)z * HEAD_E;
    const u16* rrh = p.rrh + (i64)z * HEAD_E;
    const u16* rrl = p.rrl + (i64)z * HEAD_E;

    // swizzled per-lane staging source coordinates
    const int L0 = wave * 512 + lane * 8;             // region rows 0..63
    const int L1 = 2048 + wave * 512 + lane * 8;      // region rows 64..127
    const int A0 = SWZ(L0), A1 = SWZ(L1);
    const int gr0 = A0 >> 5, gk0 = A0 & 31;
    const int gr1 = A1 >> 5, gk1 = A1 & 31;

    u16* dA0 = &Ash[wave * 512];
    u16* dA1 = &Ash[2048 + wave * 512];
    u16* dA0l = &Asl[wave * 512];
    u16* dA1l = &Asl[2048 + wave * 512];
    u16* dB0 = &Bsh[wave * 512];
    u16* dB1 = &Bsh[2048 + wave * 512];
    u16* dB0l = &Bsl[wave * 512];
    u16* dB1l = &Bsl[2048 + wave * 512];
    const int wm = (wave >> 1) * 64, wn = (wave & 1) * 64;
    const int wn2 = (wave & 1) * 32;
    const int fr = lane & 15, fk = (lane >> 4) * 8, fq = (lane >> 4) * 4;
    f32x4 acc[4][4] = {};

    // ---- phase A: AC = qu . kk^T (K=64)
    for (int k0 = 0; k0 < 64; k0 += 32) {
        __syncthreads();
        gload16(quh + (i64)(m0 + gr0) * 64 + k0 + gk0, dA0);
        gload16(quh + (i64)(m0 + gr1) * 64 + k0 + gk1, dA1);
        gload16(qul + (i64)(m0 + gr0) * 64 + k0 + gk0, dA0l);
        gload16(qul + (i64)(m0 + gr1) * 64 + k0 + gk1, dA1l);
        gload16(kkh + (i64)(n0 + gr0) * 64 + k0 + gk0, dB0);
        gload16(kkh + (i64)(n0 + gr1) * 64 + k0 + gk1, dB1);
        gload16(kkl + (i64)(n0 + gr0) * 64 + k0 + gk0, dB0l);
        gload16(kkl + (i64)(n0 + gr1) * 64 + k0 + gk1, dB1l);
        __syncthreads();
        bf16x8 fah[4], fal[4], fbh[4], fbl[4];
#pragma unroll
        for (int t = 0; t < 4; ++t) {
            fah[t] = *(const bf16x8*)&Ash[SWZ((wm + t * 16 + fr) * 32 + fk)];
            fal[t] = *(const bf16x8*)&Asl[SWZ((wm + t * 16 + fr) * 32 + fk)];
            fbh[t] = *(const bf16x8*)&Bsh[SWZ((wn + t * 16 + fr) * 32 + fk)];
            fbl[t] = *(const bf16x8*)&Bsl[SWZ((wn + t * 16 + fr) * 32 + fk)];
        }
#pragma unroll
        for (int mi = 0; mi < 4; ++mi)
#pragma unroll
            for (int ni = 0; ni < 4; ++ni) {
                acc[mi][ni] = __builtin_amdgcn_mfma_f32_16x16x32_bf16(fah[mi], fbh[ni], acc[mi][ni], 0, 0, 0);
                acc[mi][ni] = __builtin_amdgcn_mfma_f32_16x16x32_bf16(fah[mi], fbl[ni], acc[mi][ni], 0, 0, 0);
                acc[mi][ni] = __builtin_amdgcn_mfma_f32_16x16x32_bf16(fal[mi], fbh[ni], acc[mi][ni], 0, 0, 0);
            }
    }

    // ---- fixrow: B_D at r==127, d<=-2 uses Ghat row m0+128.
    const bool hasfix = (D0 <= -2);
    if (hasfix) {
        if (tid < 64) {
            const u16 hb = qvh[(i64)(m0 + 128) * 64 + tid];
            const u16 lb = qvl[(i64)(m0 + 128) * 64 + tid];
            qvrow[tid] = bf2f(hb) + bf2f(lb);
        }
        __syncthreads();
        const int c = tid >> 1, half = tid & 1;
        int colf = c - D0 - 129;                       // rr col for (127, c)
        colf = colf < 0 ? 0 : (colf > SEQ - 1 ? SEQ - 1 : colf);
        const u16* ph = rrh + (i64)colf * 64 + half * 32;
        const u16* pl = rrl + (i64)colf * 64 + half * 32;
        float s = 0.f;
#pragma unroll
        for (int k8 = 0; k8 < 4; ++k8) {
            const bf16x8 hv = *(const bf16x8*)&ph[k8 * 8];
            const bf16x8 lv = *(const bf16x8*)&pl[k8 * 8];
#pragma unroll
            for (int j = 0; j < 8; ++j)
                s += (bf2f((u16)hv[j]) + bf2f((u16)lv[j])) * qvrow[half * 32 + k8 * 8 + j];
        }
        s += __shfl_xor(s, 1);
        if (half == 0) fixrow[c] = s;
    }

    // ---- band chunks: 4 x (128 rows x 64 t-cols), K=64
    for (int ch = 0; ch < 4; ++ch) {
        f32x4 acc2[4][2] = {};
        for (int k0 = 0; k0 < 64; k0 += 32) {
            __syncthreads();   // also protects bandc/staging overlay reuse
            gload16(qvh + (i64)(m0 + gr0) * 64 + k0 + gk0, dA0);
            gload16(qvh + (i64)(m0 + gr1) * 64 + k0 + gk1, dA1);
            gload16(qvl + (i64)(m0 + gr0) * 64 + k0 + gk0, dA0l);
            gload16(qvl + (i64)(m0 + gr1) * 64 + k0 + gk1, dA1l);
            {
                const int t = ch * 64 + gr0;          // gr0 spans 0..63 over waves
                const int d = t + D0 - 127;
                int col = d >= 0 ? (SEQ - 1) - d : -d - 2;
                col = col < 0 ? 0 : (col > SEQ - 1 ? SEQ - 1 : col);
                gload16(rrh + (i64)col * 64 + k0 + gk0, dB0);
                gload16(rrl + (i64)col * 64 + k0 + gk0, dB0l);
            }
            __syncthreads();
            bf16x8 fah[4], fal[4], fbh[2], fbl[2];
#pragma unroll
            for (int t = 0; t < 4; ++t) {
                fah[t] = *(const bf16x8*)&Ash[SWZ((wm + t * 16 + fr) * 32 + fk)];
                fal[t] = *(const bf16x8*)&Asl[SWZ((wm + t * 16 + fr) * 32 + fk)];
            }
#pragma unroll
            for (int t = 0; t < 2; ++t) {
                fbh[t] = *(const bf16x8*)&Bsh[SWZ((wn2 + t * 16 + fr) * 32 + fk)];
                fbl[t] = *(const bf16x8*)&Bsl[SWZ((wn2 + t * 16 + fr) * 32 + fk)];
            }
#pragma unroll
            for (int mi = 0; mi < 4; ++mi)
#pragma unroll
                for (int ni = 0; ni < 2; ++ni) {
                    acc2[mi][ni] = __builtin_amdgcn_mfma_f32_16x16x32_bf16(fah[mi], fbh[ni], acc2[mi][ni], 0, 0, 0);
                    acc2[mi][ni] = __builtin_amdgcn_mfma_f32_16x16x32_bf16(fah[mi], fbl[ni], acc2[mi][ni], 0, 0, 0);
                    acc2[mi][ni] = __builtin_amdgcn_mfma_f32_16x16x32_bf16(fal[mi], fbh[ni], acc2[mi][ni], 0, 0, 0);
                }
        }
        __syncthreads();   // all waves done reading staging before overlay write
        // acc2 -> bandc (padded stride 66, conflict-free)
#pragma unroll
        for (int mi = 0; mi < 4; ++mi)
#pragma unroll
            for (int e = 0; e < 4; ++e)
#pragma unroll
                for (int ni = 0; ni < 2; ++ni)
                    bandc[(wm + mi * 16 + fq + e) * 66 + wn2 + ni * 16 + fr] = acc2[mi][ni][e];
        __syncthreads();
        // gather this chunk's diagonal contributions into acc
#pragma unroll
        for (int mi = 0; mi < 4; ++mi)
#pragma unroll
            for (int ni = 0; ni < 4; ++ni)
#pragma unroll
                for (int e = 0; e < 4; ++e) {
                    const int r = wm + mi * 16 + fq + e;
                    const int c = wn + ni * 16 + fr;
                    const int t = r - c + 127;
                    if ((t >> 6) != ch) continue;
                    const int d = r - c + D0;
                    float bd;
                    if (d == -1)      bd = 0.f;
                    else if (d >= 0)  bd = bandc[r * 66 + (t & 63)];
                    else              bd = (r == 127) ? fixrow[c]
                                                      : bandc[(r + 1) * 66 + (t & 63)];
                    acc[mi][ni][e] += bd;
                }
        // next chunk's first __syncthreads protects bandc overwrite
    }

    // ---- epilogue: raw scores (softmax applies scale + mask)
    float* C = p.Cf + (i64)z * SEQ * SEQ;
#pragma unroll
    for (int mi = 0; mi < 4; ++mi)
#pragma unroll
        for (int e = 0; e < 4; ++e) {
            const i64 row = m0 + wm + mi * 16 + fq + e;
#pragma unroll
            for (int ni = 0; ni < 4; ++ni)
                C[row * SEQ + n0 + wn + ni * 16 + fr] = acc[mi][ni][e];
        }
}

// ---------------------------------------------------------------------------
// Softmax normalize: wave-per-row, scale + mask + exp + sum, in place.
// ---------------------------------------------------------------------------
__global__ __launch_bounds__(256)
void softmax_norm(float* __restrict__ Wbase, const float* __restrict__ mask,
                  float* __restrict__ lrow)
{
    const int h = blockIdx.y;
    float* Wh = Wbase + (i64)h * SEQ * SEQ;
    const int wave = threadIdx.x >> 6, lane = threadIdx.x & 63;
    const int i = blockIdx.x * 4 + wave;
    const i64 rowoff = (i64)i * SEQ;
    float s[32];
    float mloc = -3.0e38f;
#pragma unroll
    for (int r = 0; r < 8; ++r) {
        const int j0 = r * 256 + lane * 4;
        const float4 wv = *(const float4*)&Wh[rowoff + j0];
        const float4 mk = *(const float4*)&mask[rowoff + j0];
        s[r * 4 + 0] = wv.x * 0.03125f + mk.x;
        s[r * 4 + 1] = wv.y * 0.03125f + mk.y;
        s[r * 4 + 2] = wv.z * 0.03125f + mk.z;
        s[r * 4 + 3] = wv.w * 0.03125f + mk.w;
        mloc = fmaxf(fmaxf(fmaxf(mloc, s[r * 4]), fmaxf(s[r * 4 + 1], s[r * 4 + 2])), s[r * 4 + 3]);
    }
#pragma unroll
    for (int o = 32; o > 0; o >>= 1) mloc = fmaxf(mloc, __shfl_xor(mloc, o));
    float lsum = 0.f;
#pragma unroll
    for (int k = 0; k < 32; ++k) { s[k] = __expf(s[k] - mloc); lsum += s[k]; }
#pragma unroll
    for (int o = 32; o > 0; o >>= 1) lsum += __shfl_xor(lsum, o);
    const float inv = 1.f / lsum;
#pragma unroll
    for (int r = 0; r < 8; ++r) {
        const int j0 = r * 256 + lane * 4;
        float4 ov;
        ov.x = s[r * 4 + 0] * inv; ov.y = s[r * 4 + 1] * inv;
        ov.z = s[r * 4 + 2] * inv; ov.w = s[r * 4 + 3] * inv;
        *(float4*)&Wh[rowoff + j0] = ov;
    }
    if (lane == 0) lrow[(i64)h * SEQ + i] = lsum;
}

// ---------------------------------------------------------------------------
// PV split-K: O_part[kz][m][z*64+d] = sum_{f in half kz} W[z][m][f]*V[z][f][d]
// ---------------------------------------------------------------------------
__global__ __launch_bounds__(256)
void mfma_pv(const float* __restrict__ Wgt, const u16* __restrict__ VTh,
             const u16* __restrict__ VTl, float* __restrict__ Opart)
{
    __shared__ __align__(16) float Asf[256 * 32];
    __shared__ __align__(16) u16 Bsh[64 * 32];
    __shared__ __align__(16) u16 Bsl[64 * 32];
    const int tid = threadIdx.x, wave = tid >> 6, lane = tid & 63;
    const int z = blockIdx.z;
    const int kz = blockIdx.x;
    const i64 m0 = (i64)blockIdx.y * 256;
    const float* A = Wgt + (i64)z * SEQ * SEQ;
    const u16* Bh = VTh + (i64)z * HEAD_E;
    const u16* Bl = VTl + (i64)z * HEAD_E;
    const int ar = tid >> 3, akc = (tid & 7) * 4;
    const int br = tid >> 2, bkc = (tid & 3) * 8;
    const int wm = wave * 64;
    f32x4 acc[4][4] = {};
    const int kbeg = kz * (SEQ / 2), kend = kbeg + SEQ / 2;

    for (int k0 = kbeg; k0 < kend; k0 += 32) {
        __syncthreads();
#pragma unroll
        for (int i = 0; i < 8; ++i)
            gload16(A + (m0 + ar + i * 32) * SEQ + k0 + akc, &Asf[(i * 256 + wave * 64) * 4]);
        gload16(Bh + (i64)br * SEQ + k0 + bkc, &Bsh[wave * 512]);
        gload16(Bl + (i64)br * SEQ + k0 + bkc, &Bsl[wave * 512]);
        __syncthreads();
        const int fr = lane & 15, fk = (lane >> 4) * 8;
        bf16x8 fbh[4], fbl[4];
#pragma unroll
        for (int t = 0; t < 4; ++t) {
            fbh[t] = *(const bf16x8*)&Bsh[(t * 16 + fr) * 32 + fk];
            fbl[t] = *(const bf16x8*)&Bsl[(t * 16 + fr) * 32 + fk];
        }
#pragma unroll
        for (int mi = 0; mi < 4; ++mi) {
            const float4 x0 = *(const float4*)&Asf[(wm + mi * 16 + fr) * 32 + fk];
            const float4 x1 = *(const float4*)&Asf[(wm + mi * 16 + fr) * 32 + fk + 4];
            float av[8] = { x0.x, x0.y, x0.z, x0.w, x1.x, x1.y, x1.z, x1.w };
            bf16x8 ah, al;
#pragma unroll
            for (int j = 0; j < 8; ++j) {
                union { float f; unsigned u; } v; v.f = av[j];
                const u16 hb = (u16)(v.u >> 16);
                union { unsigned u; float f; } fh; fh.u = v.u & 0xFFFF0000u;
                union { float f; unsigned u; } rm; rm.f = av[j] - fh.f;
                ah[j] = (short)hb;
                al[j] = (short)(u16)(rm.u >> 16);
            }
#pragma unroll
            for (int ni = 0; ni < 4; ++ni) {
                acc[mi][ni] = __builtin_amdgcn_mfma_f32_16x16x32_bf16(ah, fbh[ni], acc[mi][ni], 0, 0, 0);
                acc[mi][ni] = __builtin_amdgcn_mfma_f32_16x16x32_bf16(ah, fbl[ni], acc[mi][ni], 0, 0, 0);
                acc[mi][ni] = __builtin_amdgcn_mfma_f32_16x16x32_bf16(al, fbh[ni], acc[mi][ni], 0, 0, 0);
            }
        }
    }

    float* O = Opart + (i64)kz * IN_E;
    const int fr = lane & 15, fq = (lane >> 4) * 4;
#pragma unroll
    for (int mi = 0; mi < 4; ++mi)
#pragma unroll
        for (int e = 0; e < 4; ++e) {
            const i64 m = m0 + wm + mi * 16 + fq + e;
#pragma unroll
            for (int ni = 0; ni < 4; ++ni)
                O[m * DMODEL + z * 64 + ni * 16 + fr] = acc[mi][ni][e];
        }
}

// ---------------------------------------------------------------------------
// merge PV partials + split to bf16 hi/lo
// ---------------------------------------------------------------------------
__global__ __launch_bounds__(256)
void merge_split(const float* __restrict__ P0, const float* __restrict__ P1,
                 u16* __restrict__ oh, u16* __restrict__ ol)
{
    const int i = blockIdx.x * 256 + threadIdx.x;
    const float4 a = ((const float4*)P0)[i];
    const float4 b = ((const float4*)P1)[i];
    const float x0 = a.x + b.x, x1 = a.y + b.y, x2 = a.z + b.z, x3 = a.w + b.w;
    const u16 h0 = f2bf(x0), h1 = f2bf(x1), h2 = f2bf(x2), h3 = f2bf(x3);
    const u16 l0 = f2bf(x0 - bf2f(h0)), l1 = f2bf(x1 - bf2f(h1));
    const u16 l2 = f2bf(x2 - bf2f(h2)), l3 = f2bf(x3 - bf2f(h3));
    uint2 hh; hh.x = (unsigned)h0 | ((unsigned)h1 << 16); hh.y = (unsigned)h2 | ((unsigned)h3 << 16);
    uint2 ll; ll.x = (unsigned)l0 | ((unsigned)l1 << 16); ll.y = (unsigned)l2 | ((unsigned)l3 << 16);
    ((uint2*)oh)[i] = hh;
    ((uint2*)ol)[i] = ll;
}

// ---------------------------------------------------------------------------
// vv [h][f][d] -> vvT [h][d][f]  (bf16 hi+lo)
// ---------------------------------------------------------------------------
__global__ __launch_bounds__(256)
void transpose_vv(const u16* __restrict__ vh, const u16* __restrict__ vl,
                  u16* __restrict__ th, u16* __restrict__ tl)
{
    __shared__ u16 tile[64][65];
    const int tid = threadIdx.x;
    const int h = blockIdx.y, f0 = blockIdx.x * 64;
    const i64 src = ((i64)h * SEQ + f0) * DHEAD;
    const i64 dst = (i64)h * HEAD_E + f0;
#pragma unroll
    for (int i = 0; i < 16; ++i) {
        const int idx = i * 256 + tid;
        const int r = idx >> 6, c = idx & 63;
        tile[c][r] = vh[src + (i64)r * 64 + c];
    }
    __syncthreads();
#pragma unroll
    for (int i = 0; i < 16; ++i) {
        const int idx = i * 256 + tid;
        const int d = idx >> 6, fl = idx & 63;
        th[dst + (i64)d * SEQ + fl] = tile[d][fl];
    }
    __syncthreads();
#pragma unroll
    for (int i = 0; i < 16; ++i) {
        const int idx = i * 256 + tid;
        const int r = idx >> 6, c = idx & 63;
        tile[c][r] = vl[src + (i64)r * 64 + c];
    }
    __syncthreads();
#pragma unroll
    for (int i = 0; i < 16; ++i) {
        const int idx = i * 256 + tid;
        const int d = idx >> 6, fl = idx & 63;
        tl[dst + (i64)d * SEQ + fl] = tile[d][fl];
    }
}

// ---------------------------------------------------------------------------
// loss = mean_h ( 1 / min_i l[h][i] )
// ---------------------------------------------------------------------------
__global__ __launch_bounds__(256)
void loss_kernel(const float* __restrict__ lrow, float* __restrict__ out)
{
    __shared__ float red[4];
    const int tx = threadIdx.x, wave = tx >> 6, lane = tx & 63;
    float acc = 0.f;
    for (int h = 0; h < NHEADS; ++h) {
        float m = 3.0e38f;
#pragma unroll
        for (int k = 0; k < 8; ++k) m = fminf(m, lrow[(i64)h * SEQ + k * 256 + tx]);
#pragma unroll
        for (int o = 32; o > 0; o >>= 1) m = fminf(m, __shfl_xor(m, o));
        if (lane == 0) red[wave] = m;
        __syncthreads();
        if (tx == 0) acc += 1.f / fminf(fminf(red[0], red[1]), fminf(red[2], red[3]));
        __syncthreads();
    }
    if (tx == 0) *out = acc * (1.f / NHEADS);
}

// ---------------------------------------------------------------------------
extern "C" void kernel_launch(void* const* d_in, const int* in_sizes, int n_in,
                              void* d_out, int out_size, void* d_ws, size_t ws_size,
                              hipStream_t stream)
{
    const float* query = (const float*)d_in[0];
    const float* key   = (const float*)d_in[1];
    const float* value = (const float*)d_in[2];
    const float* mask  = (const float*)d_in[3];
    const float* Wq    = (const float*)d_in[4];
    const float* Wke   = (const float*)d_in[5];
    const float* Wkr   = (const float*)d_in[6];
    const float* Wv    = (const float*)d_in[7];
    const float* Wf    = (const float*)d_in[8];
    const float* u_p   = (const float*)d_in[9];
    const float* v_p   = (const float*)d_in[10];

    float* out_final = (float*)d_out;
    float* weights   = out_final + (i64)SEQ * DMODEL;
    float* loss      = weights + (i64)NHEADS * SEQ * SEQ;

    // workspace layout
    char* w = (char*)d_ws;
    u16* in_h = (u16*)w;               w += (i64)4 * IN_E * 2;   // [query][key][value][rel]
    u16* in_l = (u16*)w;               w += (i64)4 * IN_E * 2;
    u16* W_h  = (u16*)w;               w += (i64)5 * W_E * 2;    // [Wq][Wke][Wv][Wkr][Wf]
    u16* W_l  = (u16*)w;               w += (i64)5 * W_E * 2;
    u16* P_h  = (u16*)w;               w += (i64)4 * IN_E * 2;   // [qu][kk][vv][rr]
    u16* P_l  = (u16*)w;               w += (i64)4 * IN_E * 2;
    u16* qv_h = (u16*)w;               w += (i64)IN_E * 2;
    u16* qv_l = (u16*)w;               w += (i64)IN_E * 2;
    u16* vvT_h = (u16*)w;              w += (i64)IN_E * 2;
    u16* vvT_l = (u16*)w;              w += (i64)IN_E * 2;
    u16* o_h  = (u16*)w;               w += (i64)IN_E * 2;
    u16* o_l  = (u16*)w;               w += (i64)IN_E * 2;
    float* lrow = (float*)w;           w += (i64)NHEADS * SEQ * 4;
    float* Opart = (float*)w;          w += (i64)2 * IN_E * 4;

    dim3 blk(256);

    // split inputs + weights
    SplitArgs sa;
    sa.src[0] = query; sa.dh[0] = in_h;           sa.dl[0] = in_l;           sa.n4[0] = IN_E / 4;
    sa.src[1] = key;   sa.dh[1] = in_h + IN_E;    sa.dl[1] = in_l + IN_E;    sa.n4[1] = IN_E / 4;
    sa.src[2] = value; sa.dh[2] = in_h + 2*IN_E;  sa.dl[2] = in_l + 2*IN_E;  sa.n4[2] = IN_E / 4;
    sa.src[3] = Wq;    sa.dh[3] = W_h;            sa.dl[3] = W_l;            sa.n4[3] = W_E / 4;
    sa.src[4] = Wke;   sa.dh[4] = W_h + W_E;      sa.dl[4] = W_l + W_E;      sa.n4[4] = W_E / 4;
    sa.src[5] = Wv;    sa.dh[5] = W_h + 2*W_E;    sa.dl[5] = W_l + 2*W_E;    sa.n4[5] = W_E / 4;
    sa.src[6] = Wkr;   sa.dh[6] = W_h + 3*W_E;    sa.dl[6] = W_l + 3*W_E;    sa.n4[6] = W_E / 4;
    sa.src[7] = Wf;    sa.dh[7] = W_h + 4*W_E;    sa.dl[7] = W_l + 4*W_E;    sa.n4[7] = W_E / 4;
    split_all<<<dim3(2048, 8), blk, 0, stream>>>(sa);
    posenc_split<<<dim3(IN_E / 256), blk, 0, stream>>>(in_h + 3*(i64)IN_E, in_l + 3*(i64)IN_E);

    // projections: z in {q,k,v,r}
    {
        TNArgs p = {};
        p.Ah = in_h; p.Al = in_l; p.Bh = W_h; p.Bl = W_l;
        p.sAz = IN_E; p.sBz = W_E;
        p.O1h = P_h; p.O1l = P_l; p.O2h = qv_h; p.O2l = qv_l;
        p.b1 = u_p; p.b2 = v_p;
        p.K = DMODEL; p.mode = 1;
        mfma_tn128<<<dim3(DMODEL / 128, SEQ / 128, 4), blk, 0, stream>>>(p);
    }

    transpose_vv<<<dim3(SEQ / 64, NHEADS), blk, 0, stream>>>(
        P_h + 2*(i64)IN_E, P_l + 2*(i64)IN_E, vvT_h, vvT_l);

    // fused AC + shifted-BD scores -> raw f32 into weights region
    {
        ScoreArgs p;
        p.quh = P_h;             p.qul = P_l;
        p.kkh = P_h + IN_E;      p.kkl = P_l + IN_E;
        p.qvh = qv_h;            p.qvl = qv_l;
        p.rrh = P_h + 3*(i64)IN_E; p.rrl = P_l + 3*(i64)IN_E;
        p.Cf = weights;
        mfma_score<<<dim3(SEQ / 128, SEQ / 128, NHEADS), blk, 0, stream>>>(p);
    }

    // softmax normalize in place
    softmax_norm<<<dim3(SEQ / 4, NHEADS), blk, 0, stream>>>(weights, mask, lrow);

    // PV split-K into partials, then merge+split
    mfma_pv<<<dim3(2, SEQ / 256, NHEADS), blk, 0, stream>>>(weights, vvT_h, vvT_l, Opart);
    merge_split<<<dim3(IN_E / 4 / 256), blk, 0, stream>>>(Opart, Opart + IN_E, o_h, o_l);

    // final GEMM + GELU
    {
        TNArgs p = {};
        p.Ah = o_h; p.Al = o_l;
        p.Bh = W_h + 4*(i64)W_E; p.Bl = W_l + 4*(i64)W_E;
        p.sAz = 0; p.sBz = 0;
        p.Cf = out_final; p.sCz = 0; p.ldc = DMODEL;
        p.K = DMODEL; p.mode = 2;
        mfma_tn128<<<dim3(DMODEL / 128, SEQ / 128, 1), blk, 0, stream>>>(p);
    }

    loss_kernel<<<dim3(1), blk, 0, stream>>>(lrow, loss);
}

// Round 5
// 1314.314 us; speedup vs baseline: 1.0617x; 1.0617x over previous
//
#include <hip/hip_runtime.h>
#include <math.h>

#define SEQ 2048
#define DMODEL 1024
#define NHEADS 16
#define DHEAD 64

typedef long long i64;
typedef unsigned short u16;
typedef __attribute__((ext_vector_type(4))) float f32x4;
typedef __attribute__((ext_vector_type(8))) short bf16x8;

#define IN_E  2097152   // 2048*1024
#define W_E   1048576   // 1024*1024
#define HEAD_E 131072   // 2048*64

// ---------------------------------------------------------------------------
// bf16 split helpers
// ---------------------------------------------------------------------------
__device__ inline u16 f2bf(float x) {                // RNE
    union { float f; unsigned u; } v; v.f = x;
    unsigned r = v.u + 0x7FFF + ((v.u >> 16) & 1);
    return (u16)(r >> 16);
}
__device__ inline float bf2f(u16 h) {
    union { unsigned u; float f; } v; v.u = ((unsigned)h) << 16;
    return v.f;
}

__device__ inline void gload16(const void* g, void* l) {
    __builtin_amdgcn_global_load_lds(
        (const __attribute__((address_space(1))) unsigned int*)g,
        (__attribute__((address_space(3))) unsigned int*)l, 16, 0, 0);
}

// ---------------------------------------------------------------------------
// Split 8 f32 arrays into bf16 hi/lo. z = array id, float4 per thread.
// ---------------------------------------------------------------------------
struct SplitArgs {
    const float* src[8];
    u16* dh[8];
    u16* dl[8];
    int n4[8];
};
__global__ __launch_bounds__(256)
void split_all(SplitArgs a)
{
    const int z = blockIdx.y;
    const int i = blockIdx.x * 256 + threadIdx.x;
    if (i >= a.n4[z]) return;
    const float4 x = ((const float4*)a.src[z])[i];
    u16 h0 = f2bf(x.x), h1 = f2bf(x.y), h2 = f2bf(x.z), h3 = f2bf(x.w);
    u16 l0 = f2bf(x.x - bf2f(h0)), l1 = f2bf(x.y - bf2f(h1));
    u16 l2 = f2bf(x.z - bf2f(h2)), l3 = f2bf(x.w - bf2f(h3));
    uint2 hh; hh.x = (unsigned)h0 | ((unsigned)h1 << 16); hh.y = (unsigned)h2 | ((unsigned)h3 << 16);
    uint2 ll; ll.x = (unsigned)l0 | ((unsigned)l1 << 16); ll.y = (unsigned)l2 | ((unsigned)l3 << 16);
    ((uint2*)a.dh[z])[i] = hh;
    ((uint2*)a.dl[z])[i] = ll;
}

// ---------------------------------------------------------------------------
// rel_enc computed + split directly
// ---------------------------------------------------------------------------
__global__ __launch_bounds__(256)
void posenc_split(u16* __restrict__ dh, u16* __restrict__ dl)
{
    const int idx = blockIdx.x * 256 + threadIdx.x;
    const int f = idx >> 10;
    const int i = idx & 1023;
    const float P = (float)(SEQ - 1 - f);
    const float ex = (float)(i & ~1) * (1.f / 1024.f);
    const float dv = powf(10000.f, -ex);
    const float ang = P * dv;
    const float val = (i & 1) ? cosf(ang) : sinf(ang);
    const u16 hb = f2bf(val);
    dh[idx] = hb;
    dl[idx] = f2bf(val - bf2f(hb));
}

// ---------------------------------------------------------------------------
// Split-3 bf16 MFMA TN GEMM, 128x128 tile, BK=32.  (projections + final GELU)
// ---------------------------------------------------------------------------
struct TNArgs {
    const u16 *Ah, *Al, *Bh, *Bl;
    i64 sAz, sBz;
    float* Cf; i64 sCz; int ldc;
    u16 *O1h, *O1l, *O2h, *O2l;
    const float *b1, *b2;
    int K, mode;
};

__global__ __launch_bounds__(256)
void mfma_tn128(TNArgs p)
{
    __shared__ __align__(16) u16 Ash[128 * 32];
    __shared__ __align__(16) u16 Asl[128 * 32];
    __shared__ __align__(16) u16 Bsh[128 * 32];
    __shared__ __align__(16) u16 Bsl[128 * 32];
    const int tid = threadIdx.x, wave = tid >> 6, lane = tid & 63;
    const int z = blockIdx.z;
    const i64 m0 = (i64)blockIdx.y * 128, n0 = (i64)blockIdx.x * 128;
    const int K = p.K;
    const u16* Abh = p.Ah + (i64)z * p.sAz;
    const u16* Abl = p.Al + (i64)z * p.sAz;
    const u16* Bbh = p.Bh + (i64)z * p.sBz;
    const u16* Bbl = p.Bl + (i64)z * p.sBz;
    const int r0 = tid >> 2, kc = (tid & 3) * 8;
    const int r1 = r0 + 64;
    u16* dA0 = &Ash[wave * 512];
    u16* dA1 = &Ash[2048 + wave * 512];
    u16* dA0l = &Asl[wave * 512];
    u16* dA1l = &Asl[2048 + wave * 512];
    u16* dB0 = &Bsh[wave * 512];
    u16* dB1 = &Bsh[2048 + wave * 512];
    u16* dB0l = &Bsl[wave * 512];
    u16* dB1l = &Bsl[2048 + wave * 512];
    const int wm = (wave >> 1) * 64, wn = (wave & 1) * 64;
    f32x4 acc[4][4] = {};

    for (int k0 = 0; k0 < K; k0 += 32) {
        __syncthreads();
        const i64 ga0 = (m0 + r0) * K + k0 + kc;
        const i64 ga1 = (m0 + r1) * K + k0 + kc;
        const i64 gb0 = (n0 + r0) * K + k0 + kc;
        const i64 gb1 = (n0 + r1) * K + k0 + kc;
        gload16(Abh + ga0, dA0);  gload16(Abh + ga1, dA1);
        gload16(Abl + ga0, dA0l); gload16(Abl + ga1, dA1l);
        gload16(Bbh + gb0, dB0);  gload16(Bbh + gb1, dB1);
        gload16(Bbl + gb0, dB0l); gload16(Bbl + gb1, dB1l);
        __syncthreads();
        const int fr = lane & 15, fk = (lane >> 4) * 8;
        bf16x8 fah[4], fal[4], fbh[4], fbl[4];
#pragma unroll
        for (int t = 0; t < 4; ++t) {
            fah[t] = *(const bf16x8*)&Ash[(wm + t * 16 + fr) * 32 + fk];
            fal[t] = *(const bf16x8*)&Asl[(wm + t * 16 + fr) * 32 + fk];
            fbh[t] = *(const bf16x8*)&Bsh[(wn + t * 16 + fr) * 32 + fk];
            fbl[t] = *(const bf16x8*)&Bsl[(wn + t * 16 + fr) * 32 + fk];
        }
#pragma unroll
        for (int mi = 0; mi < 4; ++mi)
#pragma unroll
            for (int ni = 0; ni < 4; ++ni) {
                acc[mi][ni] = __builtin_amdgcn_mfma_f32_16x16x32_bf16(fah[mi], fbh[ni], acc[mi][ni], 0, 0, 0);
                acc[mi][ni] = __builtin_amdgcn_mfma_f32_16x16x32_bf16(fah[mi], fbl[ni], acc[mi][ni], 0, 0, 0);
                acc[mi][ni] = __builtin_amdgcn_mfma_f32_16x16x32_bf16(fal[mi], fbh[ni], acc[mi][ni], 0, 0, 0);
            }
    }

    const int fr = lane & 15, fq = (lane >> 4) * 4;
    if (p.mode == 0) {
        float* C = p.Cf + (i64)z * p.sCz;
#pragma unroll
        for (int mi = 0; mi < 4; ++mi)
#pragma unroll
            for (int e = 0; e < 4; ++e) {
                const i64 row = m0 + wm + mi * 16 + fq + e;
#pragma unroll
                for (int ni = 0; ni < 4; ++ni)
                    C[row * p.ldc + n0 + wn + ni * 16 + fr] = acc[mi][ni][e];
            }
    } else if (p.mode == 1) {
        const i64 obase = (i64)z * IN_E;
#pragma unroll
        for (int mi = 0; mi < 4; ++mi)
#pragma unroll
            for (int e = 0; e < 4; ++e) {
                const i64 m = m0 + wm + mi * 16 + fq + e;
#pragma unroll
                for (int ni = 0; ni < 4; ++ni) {
                    const int c = (int)n0 + wn + ni * 16 + fr;
                    const int h = c >> 6, d = c & 63;
                    const i64 off = ((i64)h * SEQ + m) * DHEAD + d;
                    float v = acc[mi][ni][e];
                    if (z == 0) v += p.b1[c];
                    const u16 hb = f2bf(v);
                    const u16 lb = f2bf(v - bf2f(hb));
                    p.O1h[obase + off] = hb;
                    p.O1l[obase + off] = lb;
                    if (z == 0) {
                        const float v2 = acc[mi][ni][e] + p.b2[c];
                        const u16 hb2 = f2bf(v2);
                        const u16 lb2 = f2bf(v2 - bf2f(hb2));
                        p.O2h[off] = hb2;
                        p.O2l[off] = lb2;
                    }
                }
            }
    } else { // mode 2: exact GELU
        float* C = p.Cf;
#pragma unroll
        for (int mi = 0; mi < 4; ++mi)
#pragma unroll
            for (int e = 0; e < 4; ++e) {
                const i64 row = m0 + wm + mi * 16 + fq + e;
#pragma unroll
                for (int ni = 0; ni < 4; ++ni) {
                    const float x = acc[mi][ni][e];
                    C[row * p.ldc + n0 + wn + ni * 16 + fr] =
                        0.5f * x * (1.f + erff(x * 0.70710678118654752f));
                }
            }
    }
}

// ---------------------------------------------------------------------------
// Fused score kernel: S = (q+u)kk^T + shift((q+v)rr^T), raw (unscaled) f32.
// B_D[i][j] depends only on (i, d=i-j):
//   d>=0 : Ghat[i  ][2047-d];  d==-1: 0;  d<=-2: Ghat[i+1][-d-2]
// Band chunks of 128x64 through bandc, which OVERLAYS the staging LDS
// (disjoint in time) -> ~34.5KB LDS -> 4 blocks/CU.
// Staging is LINEAR (coalesced global_load_lds) — R4's pre-swizzled source
// caused a 10x HBM traffic explosion (LDS-DMA needs monotonic lane addrs).
// ---------------------------------------------------------------------------
struct ScoreArgs {
    const u16 *quh, *qul, *kkh, *kkl, *qvh, *qvl, *rrh, *rrl;
    float* Cf;
};

__global__ __launch_bounds__(256, 4)
void mfma_score(ScoreArgs p)
{
    __shared__ __align__(16) u16 SMEMU[16896];        // 33792 B union
    u16* Ash = SMEMU;                                 // 128*32
    u16* Asl = SMEMU + 4096;
    u16* Bsh = SMEMU + 8192;
    u16* Bsl = SMEMU + 12288;
    float* bandc = (float*)SMEMU;                     // 128*66 overlay
    __shared__ float fixrow[128];
    __shared__ float qvrow[64];

    const int tid = threadIdx.x, wave = tid >> 6, lane = tid & 63;
    const int z = blockIdx.z;
    const int m0 = blockIdx.y * 128, n0 = blockIdx.x * 128;
    const int D0 = m0 - n0;
    const u16* quh = p.quh + (i64)z * HEAD_E;
    const u16* qul = p.qul + (i64)z * HEAD_E;
    const u16* kkh = p.kkh + (i64)z * HEAD_E;
    const u16* kkl = p.kkl + (i64)z * HEAD_E;
    const u16* qvh = p.qvh + (i64)z * HEAD_E;
    const u16* qvl = p.qvl + (i64)z * HEAD_E;
    const u16* rrh = p.rrh + (i64)z * HEAD_E;
    const u16* rrl = p.rrl + (i64)z * HEAD_E;

    const int r0 = tid >> 2, kc = (tid & 3) * 8;
    const int r1 = r0 + 64;
    u16* dA0 = &Ash[wave * 512];
    u16* dA1 = &Ash[2048 + wave * 512];
    u16* dA0l = &Asl[wave * 512];
    u16* dA1l = &Asl[2048 + wave * 512];
    u16* dB0 = &Bsh[wave * 512];
    u16* dB1 = &Bsh[2048 + wave * 512];
    u16* dB0l = &Bsl[wave * 512];
    u16* dB1l = &Bsl[2048 + wave * 512];
    const int wm = (wave >> 1) * 64, wn = (wave & 1) * 64;
    const int wn2 = (wave & 1) * 32;
    const int fr = lane & 15, fk = (lane >> 4) * 8, fq = (lane >> 4) * 4;
    f32x4 acc[4][4] = {};

    // ---- phase A: AC = qu . kk^T (K=64)
    for (int k0 = 0; k0 < 64; k0 += 32) {
        __syncthreads();
        gload16(quh + (i64)(m0 + r0) * 64 + k0 + kc, dA0);
        gload16(quh + (i64)(m0 + r1) * 64 + k0 + kc, dA1);
        gload16(qul + (i64)(m0 + r0) * 64 + k0 + kc, dA0l);
        gload16(qul + (i64)(m0 + r1) * 64 + k0 + kc, dA1l);
        gload16(kkh + (i64)(n0 + r0) * 64 + k0 + kc, dB0);
        gload16(kkh + (i64)(n0 + r1) * 64 + k0 + kc, dB1);
        gload16(kkl + (i64)(n0 + r0) * 64 + k0 + kc, dB0l);
        gload16(kkl + (i64)(n0 + r1) * 64 + k0 + kc, dB1l);
        __syncthreads();
        bf16x8 fah[4], fal[4], fbh[4], fbl[4];
#pragma unroll
        for (int t = 0; t < 4; ++t) {
            fah[t] = *(const bf16x8*)&Ash[(wm + t * 16 + fr) * 32 + fk];
            fal[t] = *(const bf16x8*)&Asl[(wm + t * 16 + fr) * 32 + fk];
            fbh[t] = *(const bf16x8*)&Bsh[(wn + t * 16 + fr) * 32 + fk];
            fbl[t] = *(const bf16x8*)&Bsl[(wn + t * 16 + fr) * 32 + fk];
        }
#pragma unroll
        for (int mi = 0; mi < 4; ++mi)
#pragma unroll
            for (int ni = 0; ni < 4; ++ni) {
                acc[mi][ni] = __builtin_amdgcn_mfma_f32_16x16x32_bf16(fah[mi], fbh[ni], acc[mi][ni], 0, 0, 0);
                acc[mi][ni] = __builtin_amdgcn_mfma_f32_16x16x32_bf16(fah[mi], fbl[ni], acc[mi][ni], 0, 0, 0);
                acc[mi][ni] = __builtin_amdgcn_mfma_f32_16x16x32_bf16(fal[mi], fbh[ni], acc[mi][ni], 0, 0, 0);
            }
    }

    // ---- fixrow: B_D at r==127, d<=-2 uses Ghat row m0+128.
    // Distributed dot: 2 threads per col (k-halves), combined via shfl.
    const bool hasfix = (D0 <= -2);
    if (hasfix) {
        if (tid < 64) {
            const u16 hb = qvh[(i64)(m0 + 128) * 64 + tid];
            const u16 lb = qvl[(i64)(m0 + 128) * 64 + tid];
            qvrow[tid] = bf2f(hb) + bf2f(lb);
        }
        __syncthreads();
        const int c = tid >> 1, half = tid & 1;
        int colf = c - D0 - 129;                       // rr col for (127, c)
        colf = colf < 0 ? 0 : (colf > SEQ - 1 ? SEQ - 1 : colf);
        const u16* ph = rrh + (i64)colf * 64 + half * 32;
        const u16* pl = rrl + (i64)colf * 64 + half * 32;
        float s = 0.f;
#pragma unroll
        for (int k8 = 0; k8 < 4; ++k8) {
            const bf16x8 hv = *(const bf16x8*)&ph[k8 * 8];
            const bf16x8 lv = *(const bf16x8*)&pl[k8 * 8];
#pragma unroll
            for (int j = 0; j < 8; ++j)
                s += (bf2f((u16)hv[j]) + bf2f((u16)lv[j])) * qvrow[half * 32 + k8 * 8 + j];
        }
        s += __shfl_xor(s, 1);
        if (half == 0) fixrow[c] = s;
    }

    // ---- band chunks: 4 x (128 rows x 64 t-cols), K=64
    for (int ch = 0; ch < 4; ++ch) {
        f32x4 acc2[4][2] = {};
        for (int k0 = 0; k0 < 64; k0 += 32) {
            __syncthreads();   // also protects bandc/staging overlay reuse
            gload16(qvh + (i64)(m0 + r0) * 64 + k0 + kc, dA0);
            gload16(qvh + (i64)(m0 + r1) * 64 + k0 + kc, dA1);
            gload16(qvl + (i64)(m0 + r0) * 64 + k0 + kc, dA0l);
            gload16(qvl + (i64)(m0 + r1) * 64 + k0 + kc, dA1l);
            {
                const int tt = tid >> 2;               // 0..63
                const int t = ch * 64 + tt;
                const int d = t + D0 - 127;
                int col = d >= 0 ? (SEQ - 1) - d : -d - 2;
                col = col < 0 ? 0 : (col > SEQ - 1 ? SEQ - 1 : col);
                gload16(rrh + (i64)col * 64 + k0 + kc, dB0);
                gload16(rrl + (i64)col * 64 + k0 + kc, dB0l);
            }
            __syncthreads();
            bf16x8 fah[4], fal[4], fbh[2], fbl[2];
#pragma unroll
            for (int t = 0; t < 4; ++t) {
                fah[t] = *(const bf16x8*)&Ash[(wm + t * 16 + fr) * 32 + fk];
                fal[t] = *(const bf16x8*)&Asl[(wm + t * 16 + fr) * 32 + fk];
            }
#pragma unroll
            for (int t = 0; t < 2; ++t) {
                fbh[t] = *(const bf16x8*)&Bsh[(wn2 + t * 16 + fr) * 32 + fk];
                fbl[t] = *(const bf16x8*)&Bsl[(wn2 + t * 16 + fr) * 32 + fk];
            }
#pragma unroll
            for (int mi = 0; mi < 4; ++mi)
#pragma unroll
                for (int ni = 0; ni < 2; ++ni) {
                    acc2[mi][ni] = __builtin_amdgcn_mfma_f32_16x16x32_bf16(fah[mi], fbh[ni], acc2[mi][ni], 0, 0, 0);
                    acc2[mi][ni] = __builtin_amdgcn_mfma_f32_16x16x32_bf16(fah[mi], fbl[ni], acc2[mi][ni], 0, 0, 0);
                    acc2[mi][ni] = __builtin_amdgcn_mfma_f32_16x16x32_bf16(fal[mi], fbh[ni], acc2[mi][ni], 0, 0, 0);
                }
        }
        __syncthreads();   // all waves done reading staging before overlay write
        // acc2 -> bandc (padded stride 66, conflict-free)
#pragma unroll
        for (int mi = 0; mi < 4; ++mi)
#pragma unroll
            for (int e = 0; e < 4; ++e)
#pragma unroll
                for (int ni = 0; ni < 2; ++ni)
                    bandc[(wm + mi * 16 + fq + e) * 66 + wn2 + ni * 16 + fr] = acc2[mi][ni][e];
        __syncthreads();
        // gather this chunk's diagonal contributions into acc
#pragma unroll
        for (int mi = 0; mi < 4; ++mi)
#pragma unroll
            for (int ni = 0; ni < 4; ++ni)
#pragma unroll
                for (int e = 0; e < 4; ++e) {
                    const int r = wm + mi * 16 + fq + e;
                    const int c = wn + ni * 16 + fr;
                    const int t = r - c + 127;
                    if ((t >> 6) != ch) continue;
                    const int d = r - c + D0;
                    float bd;
                    if (d == -1)      bd = 0.f;
                    else if (d >= 0)  bd = bandc[r * 66 + (t & 63)];
                    else              bd = (r == 127) ? fixrow[c]
                                                      : bandc[(r + 1) * 66 + (t & 63)];
                    acc[mi][ni][e] += bd;
                }
        // next chunk's first __syncthreads protects bandc overwrite
    }

    // ---- epilogue: raw scores (softmax applies scale + mask)
    float* C = p.Cf + (i64)z * SEQ * SEQ;
#pragma unroll
    for (int mi = 0; mi < 4; ++mi)
#pragma unroll
        for (int e = 0; e < 4; ++e) {
            const i64 row = m0 + wm + mi * 16 + fq + e;
#pragma unroll
            for (int ni = 0; ni < 4; ++ni)
                C[row * SEQ + n0 + wn + ni * 16 + fr] = acc[mi][ni][e];
        }
}

// ---------------------------------------------------------------------------
// Softmax normalize: wave-per-row, scale + mask + exp + sum, in place.
// ---------------------------------------------------------------------------
__global__ __launch_bounds__(256)
void softmax_norm(float* __restrict__ Wbase, const float* __restrict__ mask,
                  float* __restrict__ lrow)
{
    const int h = blockIdx.y;
    float* Wh = Wbase + (i64)h * SEQ * SEQ;
    const int wave = threadIdx.x >> 6, lane = threadIdx.x & 63;
    const int i = blockIdx.x * 4 + wave;
    const i64 rowoff = (i64)i * SEQ;
    float s[32];
    float mloc = -3.0e38f;
#pragma unroll
    for (int r = 0; r < 8; ++r) {
        const int j0 = r * 256 + lane * 4;
        const float4 wv = *(const float4*)&Wh[rowoff + j0];
        const float4 mk = *(const float4*)&mask[rowoff + j0];
        s[r * 4 + 0] = wv.x * 0.03125f + mk.x;
        s[r * 4 + 1] = wv.y * 0.03125f + mk.y;
        s[r * 4 + 2] = wv.z * 0.03125f + mk.z;
        s[r * 4 + 3] = wv.w * 0.03125f + mk.w;
        mloc = fmaxf(fmaxf(fmaxf(mloc, s[r * 4]), fmaxf(s[r * 4 + 1], s[r * 4 + 2])), s[r * 4 + 3]);
    }
#pragma unroll
    for (int o = 32; o > 0; o >>= 1) mloc = fmaxf(mloc, __shfl_xor(mloc, o));
    float lsum = 0.f;
#pragma unroll
    for (int k = 0; k < 32; ++k) { s[k] = __expf(s[k] - mloc); lsum += s[k]; }
#pragma unroll
    for (int o = 32; o > 0; o >>= 1) lsum += __shfl_xor(lsum, o);
    const float inv = 1.f / lsum;
#pragma unroll
    for (int r = 0; r < 8; ++r) {
        const int j0 = r * 256 + lane * 4;
        float4 ov;
        ov.x = s[r * 4 + 0] * inv; ov.y = s[r * 4 + 1] * inv;
        ov.z = s[r * 4 + 2] * inv; ov.w = s[r * 4 + 3] * inv;
        *(float4*)&Wh[rowoff + j0] = ov;
    }
    if (lane == 0) lrow[(i64)h * SEQ + i] = lsum;
}

// ---------------------------------------------------------------------------
// PV split-K: O_part[kz][m][z*64+d] = sum_{f in half kz} W[z][m][f]*V[z][f][d]
// ---------------------------------------------------------------------------
__global__ __launch_bounds__(256)
void mfma_pv(const float* __restrict__ Wgt, const u16* __restrict__ VTh,
             const u16* __restrict__ VTl, float* __restrict__ Opart)
{
    __shared__ __align__(16) float Asf[256 * 32];
    __shared__ __align__(16) u16 Bsh[64 * 32];
    __shared__ __align__(16) u16 Bsl[64 * 32];
    const int tid = threadIdx.x, wave = tid >> 6, lane = tid & 63;
    const int z = blockIdx.z;
    const int kz = blockIdx.x;
    const i64 m0 = (i64)blockIdx.y * 256;
    const float* A = Wgt + (i64)z * SEQ * SEQ;
    const u16* Bh = VTh + (i64)z * HEAD_E;
    const u16* Bl = VTl + (i64)z * HEAD_E;
    const int ar = tid >> 3, akc = (tid & 7) * 4;
    const int br = tid >> 2, bkc = (tid & 3) * 8;
    const int wm = wave * 64;
    f32x4 acc[4][4] = {};
    const int kbeg = kz * (SEQ / 2), kend = kbeg + SEQ / 2;

    for (int k0 = kbeg; k0 < kend; k0 += 32) {
        __syncthreads();
#pragma unroll
        for (int i = 0; i < 8; ++i)
            gload16(A + (m0 + ar + i * 32) * SEQ + k0 + akc, &Asf[(i * 256 + wave * 64) * 4]);
        gload16(Bh + (i64)br * SEQ + k0 + bkc, &Bsh[wave * 512]);
        gload16(Bl + (i64)br * SEQ + k0 + bkc, &Bsl[wave * 512]);
        __syncthreads();
        const int fr = lane & 15, fk = (lane >> 4) * 8;
        bf16x8 fbh[4], fbl[4];
#pragma unroll
        for (int t = 0; t < 4; ++t) {
            fbh[t] = *(const bf16x8*)&Bsh[(t * 16 + fr) * 32 + fk];
            fbl[t] = *(const bf16x8*)&Bsl[(t * 16 + fr) * 32 + fk];
        }
#pragma unroll
        for (int mi = 0; mi < 4; ++mi) {
            const float4 x0 = *(const float4*)&Asf[(wm + mi * 16 + fr) * 32 + fk];
            const float4 x1 = *(const float4*)&Asf[(wm + mi * 16 + fr) * 32 + fk + 4];
            float av[8] = { x0.x, x0.y, x0.z, x0.w, x1.x, x1.y, x1.z, x1.w };
            bf16x8 ah, al;
#pragma unroll
            for (int j = 0; j < 8; ++j) {
                union { float f; unsigned u; } v; v.f = av[j];
                const u16 hb = (u16)(v.u >> 16);
                union { unsigned u; float f; } fh; fh.u = v.u & 0xFFFF0000u;
                union { float f; unsigned u; } rm; rm.f = av[j] - fh.f;
                ah[j] = (short)hb;
                al[j] = (short)(u16)(rm.u >> 16);
            }
#pragma unroll
            for (int ni = 0; ni < 4; ++ni) {
                acc[mi][ni] = __builtin_amdgcn_mfma_f32_16x16x32_bf16(ah, fbh[ni], acc[mi][ni], 0, 0, 0);
                acc[mi][ni] = __builtin_amdgcn_mfma_f32_16x16x32_bf16(ah, fbl[ni], acc[mi][ni], 0, 0, 0);
                acc[mi][ni] = __builtin_amdgcn_mfma_f32_16x16x32_bf16(al, fbh[ni], acc[mi][ni], 0, 0, 0);
            }
        }
    }

    float* O = Opart + (i64)kz * IN_E;
    const int fr = lane & 15, fq = (lane >> 4) * 4;
#pragma unroll
    for (int mi = 0; mi < 4; ++mi)
#pragma unroll
        for (int e = 0; e < 4; ++e) {
            const i64 m = m0 + wm + mi * 16 + fq + e;
#pragma unroll
            for (int ni = 0; ni < 4; ++ni)
                O[m * DMODEL + z * 64 + ni * 16 + fr] = acc[mi][ni][e];
        }
}

// ---------------------------------------------------------------------------
// merge PV partials + split to bf16 hi/lo
// ---------------------------------------------------------------------------
__global__ __launch_bounds__(256)
void merge_split(const float* __restrict__ P0, const float* __restrict__ P1,
                 u16* __restrict__ oh, u16* __restrict__ ol)
{
    const int i = blockIdx.x * 256 + threadIdx.x;
    const float4 a = ((const float4*)P0)[i];
    const float4 b = ((const float4*)P1)[i];
    const float x0 = a.x + b.x, x1 = a.y + b.y, x2 = a.z + b.z, x3 = a.w + b.w;
    const u16 h0 = f2bf(x0), h1 = f2bf(x1), h2 = f2bf(x2), h3 = f2bf(x3);
    const u16 l0 = f2bf(x0 - bf2f(h0)), l1 = f2bf(x1 - bf2f(h1));
    const u16 l2 = f2bf(x2 - bf2f(h2)), l3 = f2bf(x3 - bf2f(h3));
    uint2 hh; hh.x = (unsigned)h0 | ((unsigned)h1 << 16); hh.y = (unsigned)h2 | ((unsigned)h3 << 16);
    uint2 ll; ll.x = (unsigned)l0 | ((unsigned)l1 << 16); ll.y = (unsigned)l2 | ((unsigned)l3 << 16);
    ((uint2*)oh)[i] = hh;
    ((uint2*)ol)[i] = ll;
}

// ---------------------------------------------------------------------------
// vv [h][f][d] -> vvT [h][d][f]  (bf16 hi+lo)
// ---------------------------------------------------------------------------
__global__ __launch_bounds__(256)
void transpose_vv(const u16* __restrict__ vh, const u16* __restrict__ vl,
                  u16* __restrict__ th, u16* __restrict__ tl)
{
    __shared__ u16 tile[64][65];
    const int tid = threadIdx.x;
    const int h = blockIdx.y, f0 = blockIdx.x * 64;
    const i64 src = ((i64)h * SEQ + f0) * DHEAD;
    const i64 dst = (i64)h * HEAD_E + f0;
#pragma unroll
    for (int i = 0; i < 16; ++i) {
        const int idx = i * 256 + tid;
        const int r = idx >> 6, c = idx & 63;
        tile[c][r] = vh[src + (i64)r * 64 + c];
    }
    __syncthreads();
#pragma unroll
    for (int i = 0; i < 16; ++i) {
        const int idx = i * 256 + tid;
        const int d = idx >> 6, fl = idx & 63;
        th[dst + (i64)d * SEQ + fl] = tile[d][fl];
    }
    __syncthreads();
#pragma unroll
    for (int i = 0; i < 16; ++i) {
        const int idx = i * 256 + tid;
        const int r = idx >> 6, c = idx & 63;
        tile[c][r] = vl[src + (i64)r * 64 + c];
    }
    __syncthreads();
#pragma unroll
    for (int i = 0; i < 16; ++i) {
        const int idx = i * 256 + tid;
        const int d = idx >> 6, fl = idx & 63;
        tl[dst + (i64)d * SEQ + fl] = tile[d][fl];
    }
}

// ---------------------------------------------------------------------------
// loss = mean_h ( 1 / min_i l[h][i] )
// ---------------------------------------------------------------------------
__global__ __launch_bounds__(256)
void loss_kernel(const float* __restrict__ lrow, float* __restrict__ out)
{
    __shared__ float red[4];
    const int tx = threadIdx.x, wave = tx >> 6, lane = tx & 63;
    float acc = 0.f;
    for (int h = 0; h < NHEADS; ++h) {
        float m = 3.0e38f;
#pragma unroll
        for (int k = 0; k < 8; ++k) m = fminf(m, lrow[(i64)h * SEQ + k * 256 + tx]);
#pragma unroll
        for (int o = 32; o > 0; o >>= 1) m = fminf(m, __shfl_xor(m, o));
        if (lane == 0) red[wave] = m;
        __syncthreads();
        if (tx == 0) acc += 1.f / fminf(fminf(red[0], red[1]), fminf(red[2], red[3]));
        __syncthreads();
    }
    if (tx == 0) *out = acc * (1.f / NHEADS);
}

// ---------------------------------------------------------------------------
extern "C" void kernel_launch(void* const* d_in, const int* in_sizes, int n_in,
                              void* d_out, int out_size, void* d_ws, size_t ws_size,
                              hipStream_t stream)
{
    const float* query = (const float*)d_in[0];
    const float* key   = (const float*)d_in[1];
    const float* value = (const float*)d_in[2];
    const float* mask  = (const float*)d_in[3];
    const float* Wq    = (const float*)d_in[4];
    const float* Wke   = (const float*)d_in[5];
    const float* Wkr   = (const float*)d_in[6];
    const float* Wv    = (const float*)d_in[7];
    const float* Wf    = (const float*)d_in[8];
    const float* u_p   = (const float*)d_in[9];
    const float* v_p   = (const float*)d_in[10];

    float* out_final = (float*)d_out;
    float* weights   = out_final + (i64)SEQ * DMODEL;
    float* loss      = weights + (i64)NHEADS * SEQ * SEQ;

    // workspace layout
    char* w = (char*)d_ws;
    u16* in_h = (u16*)w;               w += (i64)4 * IN_E * 2;   // [query][key][value][rel]
    u16* in_l = (u16*)w;               w += (i64)4 * IN_E * 2;
    u16* W_h  = (u16*)w;               w += (i64)5 * W_E * 2;    // [Wq][Wke][Wv][Wkr][Wf]
    u16* W_l  = (u16*)w;               w += (i64)5 * W_E * 2;
    u16* P_h  = (u16*)w;               w += (i64)4 * IN_E * 2;   // [qu][kk][vv][rr]
    u16* P_l  = (u16*)w;               w += (i64)4 * IN_E * 2;
    u16* qv_h = (u16*)w;               w += (i64)IN_E * 2;
    u16* qv_l = (u16*)w;               w += (i64)IN_E * 2;
    u16* vvT_h = (u16*)w;              w += (i64)IN_E * 2;
    u16* vvT_l = (u16*)w;              w += (i64)IN_E * 2;
    u16* o_h  = (u16*)w;               w += (i64)IN_E * 2;
    u16* o_l  = (u16*)w;               w += (i64)IN_E * 2;
    float* lrow = (float*)w;           w += (i64)NHEADS * SEQ * 4;
    float* Opart = (float*)w;          w += (i64)2 * IN_E * 4;

    dim3 blk(256);

    // split inputs + weights
    SplitArgs sa;
    sa.src[0] = query; sa.dh[0] = in_h;           sa.dl[0] = in_l;           sa.n4[0] = IN_E / 4;
    sa.src[1] = key;   sa.dh[1] = in_h + IN_E;    sa.dl[1] = in_l + IN_E;    sa.n4[1] = IN_E / 4;
    sa.src[2] = value; sa.dh[2] = in_h + 2*IN_E;  sa.dl[2] = in_l + 2*IN_E;  sa.n4[2] = IN_E / 4;
    sa.src[3] = Wq;    sa.dh[3] = W_h;            sa.dl[3] = W_l;            sa.n4[3] = W_E / 4;
    sa.src[4] = Wke;   sa.dh[4] = W_h + W_E;      sa.dl[4] = W_l + W_E;      sa.n4[4] = W_E / 4;
    sa.src[5] = Wv;    sa.dh[5] = W_h + 2*W_E;    sa.dl[5] = W_l + 2*W_E;    sa.n4[5] = W_E / 4;
    sa.src[6] = Wkr;   sa.dh[6] = W_h + 3*W_E;    sa.dl[6] = W_l + 3*W_E;    sa.n4[6] = W_E / 4;
    sa.src[7] = Wf;    sa.dh[7] = W_h + 4*W_E;    sa.dl[7] = W_l + 4*W_E;    sa.n4[7] = W_E / 4;
    split_all<<<dim3(2048, 8), blk, 0, stream>>>(sa);
    posenc_split<<<dim3(IN_E / 256), blk, 0, stream>>>(in_h + 3*(i64)IN_E, in_l + 3*(i64)IN_E);

    // projections: z in {q,k,v,r}
    {
        TNArgs p = {};
        p.Ah = in_h; p.Al = in_l; p.Bh = W_h; p.Bl = W_l;
        p.sAz = IN_E; p.sBz = W_E;
        p.O1h = P_h; p.O1l = P_l; p.O2h = qv_h; p.O2l = qv_l;
        p.b1 = u_p; p.b2 = v_p;
        p.K = DMODEL; p.mode = 1;
        mfma_tn128<<<dim3(DMODEL / 128, SEQ / 128, 4), blk, 0, stream>>>(p);
    }

    transpose_vv<<<dim3(SEQ / 64, NHEADS), blk, 0, stream>>>(
        P_h + 2*(i64)IN_E, P_l + 2*(i64)IN_E, vvT_h, vvT_l);

    // fused AC + shifted-BD scores -> raw f32 into weights region
    {
        ScoreArgs p;
        p.quh = P_h;             p.qul = P_l;
        p.kkh = P_h + IN_E;      p.kkl = P_l + IN_E;
        p.qvh = qv_h;            p.qvl = qv_l;
        p.rrh = P_h + 3*(i64)IN_E; p.rrl = P_l + 3*(i64)IN_E;
        p.Cf = weights;
        mfma_score<<<dim3(SEQ / 128, SEQ / 128, NHEADS), blk, 0, stream>>>(p);
    }

    // softmax normalize in place
    softmax_norm<<<dim3(SEQ / 4, NHEADS), blk, 0, stream>>>(weights, mask, lrow);

    // PV split-K into partials, then merge+split
    mfma_pv<<<dim3(2, SEQ / 256, NHEADS), blk, 0, stream>>>(weights, vvT_h, vvT_l, Opart);
    merge_split<<<dim3(IN_E / 4 / 256), blk, 0, stream>>>(Opart, Opart + IN_E, o_h, o_l);

    // final GEMM + GELU
    {
        TNArgs p = {};
        p.Ah = o_h; p.Al = o_l;
        p.Bh = W_h + 4*(i64)W_E; p.Bl = W_l + 4*(i64)W_E;
        p.sAz = 0; p.sBz = 0;
        p.Cf = out_final; p.sCz = 0; p.ldc = DMODEL;
        p.K = DMODEL; p.mode = 2;
        mfma_tn128<<<dim3(DMODEL / 128, SEQ / 128, 1), blk, 0, stream>>>(p);
    }

    loss_kernel<<<dim3(1), blk, 0, stream>>>(lrow, loss);
}

// Round 6
// 912.106 us; speedup vs baseline: 1.5299x; 1.4410x over previous
//
#include <hip/hip_runtime.h>
#include <math.h>

#define SEQ 2048
#define DMODEL 1024
#define NHEADS 16
#define DHEAD 64

typedef long long i64;
typedef unsigned short u16;
typedef __attribute__((ext_vector_type(4))) float f32x4;
typedef __attribute__((ext_vector_type(8))) short bf16x8;

#define IN_E  2097152   // 2048*1024
#define W_E   1048576   // 1024*1024
#define HEAD_E 131072   // 2048*64

// ---------------------------------------------------------------------------
// bf16 split helpers
// ---------------------------------------------------------------------------
__device__ inline u16 f2bf(float x) {                // RNE
    union { float f; unsigned u; } v; v.f = x;
    unsigned r = v.u + 0x7FFF + ((v.u >> 16) & 1);
    return (u16)(r >> 16);
}
__device__ inline float bf2f(u16 h) {
    union { unsigned u; float f; } v; v.u = ((unsigned)h) << 16;
    return v.f;
}

__device__ inline void gload16(const void* g, void* l) {
    __builtin_amdgcn_global_load_lds(
        (const __attribute__((address_space(1))) unsigned int*)g,
        (__attribute__((address_space(3))) unsigned int*)l, 16, 0, 0);
}

// ---------------------------------------------------------------------------
// Split 8 f32 arrays into bf16 hi/lo. z = array id, float4 per thread.
// ---------------------------------------------------------------------------
struct SplitArgs {
    const float* src[8];
    u16* dh[8];
    u16* dl[8];
    int n4[8];
};
__global__ __launch_bounds__(256)
void split_all(SplitArgs a)
{
    const int z = blockIdx.y;
    const int i = blockIdx.x * 256 + threadIdx.x;
    if (i >= a.n4[z]) return;
    const float4 x = ((const float4*)a.src[z])[i];
    u16 h0 = f2bf(x.x), h1 = f2bf(x.y), h2 = f2bf(x.z), h3 = f2bf(x.w);
    u16 l0 = f2bf(x.x - bf2f(h0)), l1 = f2bf(x.y - bf2f(h1));
    u16 l2 = f2bf(x.z - bf2f(h2)), l3 = f2bf(x.w - bf2f(h3));
    uint2 hh; hh.x = (unsigned)h0 | ((unsigned)h1 << 16); hh.y = (unsigned)h2 | ((unsigned)h3 << 16);
    uint2 ll; ll.x = (unsigned)l0 | ((unsigned)l1 << 16); ll.y = (unsigned)l2 | ((unsigned)l3 << 16);
    ((uint2*)a.dh[z])[i] = hh;
    ((uint2*)a.dl[z])[i] = ll;
}

// ---------------------------------------------------------------------------
// rel_enc computed + split directly
// ---------------------------------------------------------------------------
__global__ __launch_bounds__(256)
void posenc_split(u16* __restrict__ dh, u16* __restrict__ dl)
{
    const int idx = blockIdx.x * 256 + threadIdx.x;
    const int f = idx >> 10;
    const int i = idx & 1023;
    const float P = (float)(SEQ - 1 - f);
    const float ex = (float)(i & ~1) * (1.f / 1024.f);
    const float dv = powf(10000.f, -ex);
    const float ang = P * dv;
    const float val = (i & 1) ? cosf(ang) : sinf(ang);
    const u16 hb = f2bf(val);
    dh[idx] = hb;
    dl[idx] = f2bf(val - bf2f(hb));
}

// ---------------------------------------------------------------------------
// Split-3 bf16 MFMA TN GEMM, 128x128 tile, BK=32.  (projections + final GELU)
// ---------------------------------------------------------------------------
struct TNArgs {
    const u16 *Ah, *Al, *Bh, *Bl;
    i64 sAz, sBz;
    float* Cf; i64 sCz; int ldc;
    u16 *O1h, *O1l, *O2h, *O2l;
    const float *b1, *b2;
    int K, mode;
};

__global__ __launch_bounds__(256)
void mfma_tn128(TNArgs p)
{
    __shared__ __align__(16) u16 Ash[128 * 32];
    __shared__ __align__(16) u16 Asl[128 * 32];
    __shared__ __align__(16) u16 Bsh[128 * 32];
    __shared__ __align__(16) u16 Bsl[128 * 32];
    const int tid = threadIdx.x, wave = tid >> 6, lane = tid & 63;
    const int z = blockIdx.z;
    const i64 m0 = (i64)blockIdx.y * 128, n0 = (i64)blockIdx.x * 128;
    const int K = p.K;
    const u16* Abh = p.Ah + (i64)z * p.sAz;
    const u16* Abl = p.Al + (i64)z * p.sAz;
    const u16* Bbh = p.Bh + (i64)z * p.sBz;
    const u16* Bbl = p.Bl + (i64)z * p.sBz;
    const int r0 = tid >> 2, kc = (tid & 3) * 8;
    const int r1 = r0 + 64;
    u16* dA0 = &Ash[wave * 512];
    u16* dA1 = &Ash[2048 + wave * 512];
    u16* dA0l = &Asl[wave * 512];
    u16* dA1l = &Asl[2048 + wave * 512];
    u16* dB0 = &Bsh[wave * 512];
    u16* dB1 = &Bsh[2048 + wave * 512];
    u16* dB0l = &Bsl[wave * 512];
    u16* dB1l = &Bsl[2048 + wave * 512];
    const int wm = (wave >> 1) * 64, wn = (wave & 1) * 64;
    f32x4 acc[4][4] = {};

    for (int k0 = 0; k0 < K; k0 += 32) {
        __syncthreads();
        const i64 ga0 = (m0 + r0) * K + k0 + kc;
        const i64 ga1 = (m0 + r1) * K + k0 + kc;
        const i64 gb0 = (n0 + r0) * K + k0 + kc;
        const i64 gb1 = (n0 + r1) * K + k0 + kc;
        gload16(Abh + ga0, dA0);  gload16(Abh + ga1, dA1);
        gload16(Abl + ga0, dA0l); gload16(Abl + ga1, dA1l);
        gload16(Bbh + gb0, dB0);  gload16(Bbh + gb1, dB1);
        gload16(Bbl + gb0, dB0l); gload16(Bbl + gb1, dB1l);
        __syncthreads();
        const int fr = lane & 15, fk = (lane >> 4) * 8;
        bf16x8 fah[4], fal[4], fbh[4], fbl[4];
#pragma unroll
        for (int t = 0; t < 4; ++t) {
            fah[t] = *(const bf16x8*)&Ash[(wm + t * 16 + fr) * 32 + fk];
            fal[t] = *(const bf16x8*)&Asl[(wm + t * 16 + fr) * 32 + fk];
            fbh[t] = *(const bf16x8*)&Bsh[(wn + t * 16 + fr) * 32 + fk];
            fbl[t] = *(const bf16x8*)&Bsl[(wn + t * 16 + fr) * 32 + fk];
        }
#pragma unroll
        for (int mi = 0; mi < 4; ++mi)
#pragma unroll
            for (int ni = 0; ni < 4; ++ni) {
                acc[mi][ni] = __builtin_amdgcn_mfma_f32_16x16x32_bf16(fah[mi], fbh[ni], acc[mi][ni], 0, 0, 0);
                acc[mi][ni] = __builtin_amdgcn_mfma_f32_16x16x32_bf16(fah[mi], fbl[ni], acc[mi][ni], 0, 0, 0);
                acc[mi][ni] = __builtin_amdgcn_mfma_f32_16x16x32_bf16(fal[mi], fbh[ni], acc[mi][ni], 0, 0, 0);
            }
    }

    const int fr = lane & 15, fq = (lane >> 4) * 4;
    if (p.mode == 0) {
        float* C = p.Cf + (i64)z * p.sCz;
#pragma unroll
        for (int mi = 0; mi < 4; ++mi)
#pragma unroll
            for (int e = 0; e < 4; ++e) {
                const i64 row = m0 + wm + mi * 16 + fq + e;
#pragma unroll
                for (int ni = 0; ni < 4; ++ni)
                    C[row * p.ldc + n0 + wn + ni * 16 + fr] = acc[mi][ni][e];
            }
    } else if (p.mode == 1) {
        const i64 obase = (i64)z * IN_E;
#pragma unroll
        for (int mi = 0; mi < 4; ++mi)
#pragma unroll
            for (int e = 0; e < 4; ++e) {
                const i64 m = m0 + wm + mi * 16 + fq + e;
#pragma unroll
                for (int ni = 0; ni < 4; ++ni) {
                    const int c = (int)n0 + wn + ni * 16 + fr;
                    const int h = c >> 6, d = c & 63;
                    const i64 off = ((i64)h * SEQ + m) * DHEAD + d;
                    float v = acc[mi][ni][e];
                    if (z == 0) v += p.b1[c];
                    const u16 hb = f2bf(v);
                    const u16 lb = f2bf(v - bf2f(hb));
                    p.O1h[obase + off] = hb;
                    p.O1l[obase + off] = lb;
                    if (z == 0) {
                        const float v2 = acc[mi][ni][e] + p.b2[c];
                        const u16 hb2 = f2bf(v2);
                        const u16 lb2 = f2bf(v2 - bf2f(hb2));
                        p.O2h[off] = hb2;
                        p.O2l[off] = lb2;
                    }
                }
            }
    } else { // mode 2: exact GELU
        float* C = p.Cf;
#pragma unroll
        for (int mi = 0; mi < 4; ++mi)
#pragma unroll
            for (int e = 0; e < 4; ++e) {
                const i64 row = m0 + wm + mi * 16 + fq + e;
#pragma unroll
                for (int ni = 0; ni < 4; ++ni) {
                    const float x = acc[mi][ni][e];
                    C[row * p.ldc + n0 + wn + ni * 16 + fr] =
                        0.5f * x * (1.f + erff(x * 0.70710678118654752f));
                }
            }
    }
}

// ---------------------------------------------------------------------------
// Fused score kernel: S = (q+u)kk^T + shift((q+v)rr^T), raw (unscaled) f32.
// B_D[i][j] depends only on (i, d=i-j):
//   d>=0 : Ghat[i  ][2047-d];  d==-1: 0;  d<=-2: Ghat[i+1][-d-2]
// Band chunks of 128x64 through bandc, which OVERLAYS the staging LDS
// (disjoint in time) -> ~34.5KB LDS -> 4 blocks/CU by LDS.
// __launch_bounds__(256,2): R4/R5's (256,4) capped VGPR at 64 -> scratch
// spills -> ~800MB extra HBM FETCH+WRITE each (the R4/R5 regression).
// (256,2) gives the allocator room (R3: 128 VGPR, no spill); occupancy is
// then resource-limited at 4 blocks/CU (128 VGPR, 34.8KB LDS).
// ---------------------------------------------------------------------------
struct ScoreArgs {
    const u16 *quh, *qul, *kkh, *kkl, *qvh, *qvl, *rrh, *rrl;
    float* Cf;
};

__global__ __launch_bounds__(256, 2)
void mfma_score(ScoreArgs p)
{
    __shared__ __align__(16) u16 SMEMU[16896];        // 33792 B union
    u16* Ash = SMEMU;                                 // 128*32
    u16* Asl = SMEMU + 4096;
    u16* Bsh = SMEMU + 8192;
    u16* Bsl = SMEMU + 12288;
    float* bandc = (float*)SMEMU;                     // 128*66 overlay
    __shared__ float fixrow[128];
    __shared__ float qvrow[64];

    const int tid = threadIdx.x, wave = tid >> 6, lane = tid & 63;
    const int z = blockIdx.z;
    const int m0 = blockIdx.y * 128, n0 = blockIdx.x * 128;
    const int D0 = m0 - n0;
    const u16* quh = p.quh + (i64)z * HEAD_E;
    const u16* qul = p.qul + (i64)z * HEAD_E;
    const u16* kkh = p.kkh + (i64)z * HEAD_E;
    const u16* kkl = p.kkl + (i64)z * HEAD_E;
    const u16* qvh = p.qvh + (i64)z * HEAD_E;
    const u16* qvl = p.qvl + (i64)z * HEAD_E;
    const u16* rrh = p.rrh + (i64)z * HEAD_E;
    const u16* rrl = p.rrl + (i64)z * HEAD_E;

    const int r0 = tid >> 2, kc = (tid & 3) * 8;
    const int r1 = r0 + 64;
    u16* dA0 = &Ash[wave * 512];
    u16* dA1 = &Ash[2048 + wave * 512];
    u16* dA0l = &Asl[wave * 512];
    u16* dA1l = &Asl[2048 + wave * 512];
    u16* dB0 = &Bsh[wave * 512];
    u16* dB1 = &Bsh[2048 + wave * 512];
    u16* dB0l = &Bsl[wave * 512];
    u16* dB1l = &Bsl[2048 + wave * 512];
    const int wm = (wave >> 1) * 64, wn = (wave & 1) * 64;
    const int wn2 = (wave & 1) * 32;
    const int fr = lane & 15, fk = (lane >> 4) * 8, fq = (lane >> 4) * 4;
    f32x4 acc[4][4] = {};

    // ---- phase A: AC = qu . kk^T (K=64)
    for (int k0 = 0; k0 < 64; k0 += 32) {
        __syncthreads();
        gload16(quh + (i64)(m0 + r0) * 64 + k0 + kc, dA0);
        gload16(quh + (i64)(m0 + r1) * 64 + k0 + kc, dA1);
        gload16(qul + (i64)(m0 + r0) * 64 + k0 + kc, dA0l);
        gload16(qul + (i64)(m0 + r1) * 64 + k0 + kc, dA1l);
        gload16(kkh + (i64)(n0 + r0) * 64 + k0 + kc, dB0);
        gload16(kkh + (i64)(n0 + r1) * 64 + k0 + kc, dB1);
        gload16(kkl + (i64)(n0 + r0) * 64 + k0 + kc, dB0l);
        gload16(kkl + (i64)(n0 + r1) * 64 + k0 + kc, dB1l);
        __syncthreads();
        bf16x8 fah[4], fal[4], fbh[4], fbl[4];
#pragma unroll
        for (int t = 0; t < 4; ++t) {
            fah[t] = *(const bf16x8*)&Ash[(wm + t * 16 + fr) * 32 + fk];
            fal[t] = *(const bf16x8*)&Asl[(wm + t * 16 + fr) * 32 + fk];
            fbh[t] = *(const bf16x8*)&Bsh[(wn + t * 16 + fr) * 32 + fk];
            fbl[t] = *(const bf16x8*)&Bsl[(wn + t * 16 + fr) * 32 + fk];
        }
#pragma unroll
        for (int mi = 0; mi < 4; ++mi)
#pragma unroll
            for (int ni = 0; ni < 4; ++ni) {
                acc[mi][ni] = __builtin_amdgcn_mfma_f32_16x16x32_bf16(fah[mi], fbh[ni], acc[mi][ni], 0, 0, 0);
                acc[mi][ni] = __builtin_amdgcn_mfma_f32_16x16x32_bf16(fah[mi], fbl[ni], acc[mi][ni], 0, 0, 0);
                acc[mi][ni] = __builtin_amdgcn_mfma_f32_16x16x32_bf16(fal[mi], fbh[ni], acc[mi][ni], 0, 0, 0);
            }
    }

    // ---- fixrow: B_D at r==127, d<=-2 uses Ghat row m0+128.
    // Distributed dot: 2 threads per col (k-halves), combined via shfl.
    const bool hasfix = (D0 <= -2);
    if (hasfix) {
        if (tid < 64) {
            const u16 hb = qvh[(i64)(m0 + 128) * 64 + tid];
            const u16 lb = qvl[(i64)(m0 + 128) * 64 + tid];
            qvrow[tid] = bf2f(hb) + bf2f(lb);
        }
        __syncthreads();
        const int c = tid >> 1, half = tid & 1;
        int colf = c - D0 - 129;                       // rr col for (127, c)
        colf = colf < 0 ? 0 : (colf > SEQ - 1 ? SEQ - 1 : colf);
        const u16* ph = rrh + (i64)colf * 64 + half * 32;
        const u16* pl = rrl + (i64)colf * 64 + half * 32;
        float s = 0.f;
#pragma unroll
        for (int k8 = 0; k8 < 4; ++k8) {
            const bf16x8 hv = *(const bf16x8*)&ph[k8 * 8];
            const bf16x8 lv = *(const bf16x8*)&pl[k8 * 8];
#pragma unroll
            for (int j = 0; j < 8; ++j)
                s += (bf2f((u16)hv[j]) + bf2f((u16)lv[j])) * qvrow[half * 32 + k8 * 8 + j];
        }
        s += __shfl_xor(s, 1);
        if (half == 0) fixrow[c] = s;
    }

    // ---- band chunks: 4 x (128 rows x 64 t-cols), K=64
    for (int ch = 0; ch < 4; ++ch) {
        f32x4 acc2[4][2] = {};
        for (int k0 = 0; k0 < 64; k0 += 32) {
            __syncthreads();   // also protects bandc/staging overlay reuse
            gload16(qvh + (i64)(m0 + r0) * 64 + k0 + kc, dA0);
            gload16(qvh + (i64)(m0 + r1) * 64 + k0 + kc, dA1);
            gload16(qvl + (i64)(m0 + r0) * 64 + k0 + kc, dA0l);
            gload16(qvl + (i64)(m0 + r1) * 64 + k0 + kc, dA1l);
            {
                const int tt = tid >> 2;               // 0..63
                const int t = ch * 64 + tt;
                const int d = t + D0 - 127;
                int col = d >= 0 ? (SEQ - 1) - d : -d - 2;
                col = col < 0 ? 0 : (col > SEQ - 1 ? SEQ - 1 : col);
                gload16(rrh + (i64)col * 64 + k0 + kc, dB0);
                gload16(rrl + (i64)col * 64 + k0 + kc, dB0l);
            }
            __syncthreads();
            bf16x8 fah[4], fal[4], fbh[2], fbl[2];
#pragma unroll
            for (int t = 0; t < 4; ++t) {
                fah[t] = *(const bf16x8*)&Ash[(wm + t * 16 + fr) * 32 + fk];
                fal[t] = *(const bf16x8*)&Asl[(wm + t * 16 + fr) * 32 + fk];
            }
#pragma unroll
            for (int t = 0; t < 2; ++t) {
                fbh[t] = *(const bf16x8*)&Bsh[(wn2 + t * 16 + fr) * 32 + fk];
                fbl[t] = *(const bf16x8*)&Bsl[(wn2 + t * 16 + fr) * 32 + fk];
            }
#pragma unroll
            for (int mi = 0; mi < 4; ++mi)
#pragma unroll
                for (int ni = 0; ni < 2; ++ni) {
                    acc2[mi][ni] = __builtin_amdgcn_mfma_f32_16x16x32_bf16(fah[mi], fbh[ni], acc2[mi][ni], 0, 0, 0);
                    acc2[mi][ni] = __builtin_amdgcn_mfma_f32_16x16x32_bf16(fah[mi], fbl[ni], acc2[mi][ni], 0, 0, 0);
                    acc2[mi][ni] = __builtin_amdgcn_mfma_f32_16x16x32_bf16(fal[mi], fbh[ni], acc2[mi][ni], 0, 0, 0);
                }
        }
        __syncthreads();   // all waves done reading staging before overlay write
        // acc2 -> bandc (padded stride 66, conflict-free)
#pragma unroll
        for (int mi = 0; mi < 4; ++mi)
#pragma unroll
            for (int e = 0; e < 4; ++e)
#pragma unroll
                for (int ni = 0; ni < 2; ++ni)
                    bandc[(wm + mi * 16 + fq + e) * 66 + wn2 + ni * 16 + fr] = acc2[mi][ni][e];
        __syncthreads();
        // gather this chunk's diagonal contributions into acc
#pragma unroll
        for (int mi = 0; mi < 4; ++mi)
#pragma unroll
            for (int ni = 0; ni < 4; ++ni)
#pragma unroll
                for (int e = 0; e < 4; ++e) {
                    const int r = wm + mi * 16 + fq + e;
                    const int c = wn + ni * 16 + fr;
                    const int t = r - c + 127;
                    if ((t >> 6) != ch) continue;
                    const int d = r - c + D0;
                    float bd;
                    if (d == -1)      bd = 0.f;
                    else if (d >= 0)  bd = bandc[r * 66 + (t & 63)];
                    else              bd = (r == 127) ? fixrow[c]
                                                      : bandc[(r + 1) * 66 + (t & 63)];
                    acc[mi][ni][e] += bd;
                }
        // next chunk's first __syncthreads protects bandc overwrite
    }

    // ---- epilogue: raw scores (softmax applies scale + mask)
    float* C = p.Cf + (i64)z * SEQ * SEQ;
#pragma unroll
    for (int mi = 0; mi < 4; ++mi)
#pragma unroll
        for (int e = 0; e < 4; ++e) {
            const i64 row = m0 + wm + mi * 16 + fq + e;
#pragma unroll
            for (int ni = 0; ni < 4; ++ni)
                C[row * SEQ + n0 + wn + ni * 16 + fr] = acc[mi][ni][e];
        }
}

// ---------------------------------------------------------------------------
// Softmax normalize: wave-per-row, scale + mask + exp + sum, in place.
// ---------------------------------------------------------------------------
__global__ __launch_bounds__(256)
void softmax_norm(float* __restrict__ Wbase, const float* __restrict__ mask,
                  float* __restrict__ lrow)
{
    const int h = blockIdx.y;
    float* Wh = Wbase + (i64)h * SEQ * SEQ;
    const int wave = threadIdx.x >> 6, lane = threadIdx.x & 63;
    const int i = blockIdx.x * 4 + wave;
    const i64 rowoff = (i64)i * SEQ;
    float s[32];
    float mloc = -3.0e38f;
#pragma unroll
    for (int r = 0; r < 8; ++r) {
        const int j0 = r * 256 + lane * 4;
        const float4 wv = *(const float4*)&Wh[rowoff + j0];
        const float4 mk = *(const float4*)&mask[rowoff + j0];
        s[r * 4 + 0] = wv.x * 0.03125f + mk.x;
        s[r * 4 + 1] = wv.y * 0.03125f + mk.y;
        s[r * 4 + 2] = wv.z * 0.03125f + mk.z;
        s[r * 4 + 3] = wv.w * 0.03125f + mk.w;
        mloc = fmaxf(fmaxf(fmaxf(mloc, s[r * 4]), fmaxf(s[r * 4 + 1], s[r * 4 + 2])), s[r * 4 + 3]);
    }
#pragma unroll
    for (int o = 32; o > 0; o >>= 1) mloc = fmaxf(mloc, __shfl_xor(mloc, o));
    float lsum = 0.f;
#pragma unroll
    for (int k = 0; k < 32; ++k) { s[k] = __expf(s[k] - mloc); lsum += s[k]; }
#pragma unroll
    for (int o = 32; o > 0; o >>= 1) lsum += __shfl_xor(lsum, o);
    const float inv = 1.f / lsum;
#pragma unroll
    for (int r = 0; r < 8; ++r) {
        const int j0 = r * 256 + lane * 4;
        float4 ov;
        ov.x = s[r * 4 + 0] * inv; ov.y = s[r * 4 + 1] * inv;
        ov.z = s[r * 4 + 2] * inv; ov.w = s[r * 4 + 3] * inv;
        *(float4*)&Wh[rowoff + j0] = ov;
    }
    if (lane == 0) lrow[(i64)h * SEQ + i] = lsum;
}

// ---------------------------------------------------------------------------
// PV split-K: O_part[kz][m][z*64+d] = sum_{f in half kz} W[z][m][f]*V[z][f][d]
// ---------------------------------------------------------------------------
__global__ __launch_bounds__(256)
void mfma_pv(const float* __restrict__ Wgt, const u16* __restrict__ VTh,
             const u16* __restrict__ VTl, float* __restrict__ Opart)
{
    __shared__ __align__(16) float Asf[256 * 32];
    __shared__ __align__(16) u16 Bsh[64 * 32];
    __shared__ __align__(16) u16 Bsl[64 * 32];
    const int tid = threadIdx.x, wave = tid >> 6, lane = tid & 63;
    const int z = blockIdx.z;
    const int kz = blockIdx.x;
    const i64 m0 = (i64)blockIdx.y * 256;
    const float* A = Wgt + (i64)z * SEQ * SEQ;
    const u16* Bh = VTh + (i64)z * HEAD_E;
    const u16* Bl = VTl + (i64)z * HEAD_E;
    const int ar = tid >> 3, akc = (tid & 7) * 4;
    const int br = tid >> 2, bkc = (tid & 3) * 8;
    const int wm = wave * 64;
    f32x4 acc[4][4] = {};
    const int kbeg = kz * (SEQ / 2), kend = kbeg + SEQ / 2;

    for (int k0 = kbeg; k0 < kend; k0 += 32) {
        __syncthreads();
#pragma unroll
        for (int i = 0; i < 8; ++i)
            gload16(A + (m0 + ar + i * 32) * SEQ + k0 + akc, &Asf[(i * 256 + wave * 64) * 4]);
        gload16(Bh + (i64)br * SEQ + k0 + bkc, &Bsh[wave * 512]);
        gload16(Bl + (i64)br * SEQ + k0 + bkc, &Bsl[wave * 512]);
        __syncthreads();
        const int fr = lane & 15, fk = (lane >> 4) * 8;
        bf16x8 fbh[4], fbl[4];
#pragma unroll
        for (int t = 0; t < 4; ++t) {
            fbh[t] = *(const bf16x8*)&Bsh[(t * 16 + fr) * 32 + fk];
            fbl[t] = *(const bf16x8*)&Bsl[(t * 16 + fr) * 32 + fk];
        }
#pragma unroll
        for (int mi = 0; mi < 4; ++mi) {
            const float4 x0 = *(const float4*)&Asf[(wm + mi * 16 + fr) * 32 + fk];
            const float4 x1 = *(const float4*)&Asf[(wm + mi * 16 + fr) * 32 + fk + 4];
            float av[8] = { x0.x, x0.y, x0.z, x0.w, x1.x, x1.y, x1.z, x1.w };
            bf16x8 ah, al;
#pragma unroll
            for (int j = 0; j < 8; ++j) {
                union { float f; unsigned u; } v; v.f = av[j];
                const u16 hb = (u16)(v.u >> 16);
                union { unsigned u; float f; } fh; fh.u = v.u & 0xFFFF0000u;
                union { float f; unsigned u; } rm; rm.f = av[j] - fh.f;
                ah[j] = (short)hb;
                al[j] = (short)(u16)(rm.u >> 16);
            }
#pragma unroll
            for (int ni = 0; ni < 4; ++ni) {
                acc[mi][ni] = __builtin_amdgcn_mfma_f32_16x16x32_bf16(ah, fbh[ni], acc[mi][ni], 0, 0, 0);
                acc[mi][ni] = __builtin_amdgcn_mfma_f32_16x16x32_bf16(ah, fbl[ni], acc[mi][ni], 0, 0, 0);
                acc[mi][ni] = __builtin_amdgcn_mfma_f32_16x16x32_bf16(al, fbh[ni], acc[mi][ni], 0, 0, 0);
            }
        }
    }

    float* O = Opart + (i64)kz * IN_E;
    const int fr = lane & 15, fq = (lane >> 4) * 4;
#pragma unroll
    for (int mi = 0; mi < 4; ++mi)
#pragma unroll
        for (int e = 0; e < 4; ++e) {
            const i64 m = m0 + wm + mi * 16 + fq + e;
#pragma unroll
            for (int ni = 0; ni < 4; ++ni)
                O[m * DMODEL + z * 64 + ni * 16 + fr] = acc[mi][ni][e];
        }
}

// ---------------------------------------------------------------------------
// merge PV partials + split to bf16 hi/lo
// ---------------------------------------------------------------------------
__global__ __launch_bounds__(256)
void merge_split(const float* __restrict__ P0, const float* __restrict__ P1,
                 u16* __restrict__ oh, u16* __restrict__ ol)
{
    const int i = blockIdx.x * 256 + threadIdx.x;
    const float4 a = ((const float4*)P0)[i];
    const float4 b = ((const float4*)P1)[i];
    const float x0 = a.x + b.x, x1 = a.y + b.y, x2 = a.z + b.z, x3 = a.w + b.w;
    const u16 h0 = f2bf(x0), h1 = f2bf(x1), h2 = f2bf(x2), h3 = f2bf(x3);
    const u16 l0 = f2bf(x0 - bf2f(h0)), l1 = f2bf(x1 - bf2f(h1));
    const u16 l2 = f2bf(x2 - bf2f(h2)), l3 = f2bf(x3 - bf2f(h3));
    uint2 hh; hh.x = (unsigned)h0 | ((unsigned)h1 << 16); hh.y = (unsigned)h2 | ((unsigned)h3 << 16);
    uint2 ll; ll.x = (unsigned)l0 | ((unsigned)l1 << 16); ll.y = (unsigned)l2 | ((unsigned)l3 << 16);
    ((uint2*)oh)[i] = hh;
    ((uint2*)ol)[i] = ll;
}

// ---------------------------------------------------------------------------
// vv [h][f][d] -> vvT [h][d][f]  (bf16 hi+lo)
// ---------------------------------------------------------------------------
__global__ __launch_bounds__(256)
void transpose_vv(const u16* __restrict__ vh, const u16* __restrict__ vl,
                  u16* __restrict__ th, u16* __restrict__ tl)
{
    __shared__ u16 tile[64][65];
    const int tid = threadIdx.x;
    const int h = blockIdx.y, f0 = blockIdx.x * 64;
    const i64 src = ((i64)h * SEQ + f0) * DHEAD;
    const i64 dst = (i64)h * HEAD_E + f0;
#pragma unroll
    for (int i = 0; i < 16; ++i) {
        const int idx = i * 256 + tid;
        const int r = idx >> 6, c = idx & 63;
        tile[c][r] = vh[src + (i64)r * 64 + c];
    }
    __syncthreads();
#pragma unroll
    for (int i = 0; i < 16; ++i) {
        const int idx = i * 256 + tid;
        const int d = idx >> 6, fl = idx & 63;
        th[dst + (i64)d * SEQ + fl] = tile[d][fl];
    }
    __syncthreads();
#pragma unroll
    for (int i = 0; i < 16; ++i) {
        const int idx = i * 256 + tid;
        const int r = idx >> 6, c = idx & 63;
        tile[c][r] = vl[src + (i64)r * 64 + c];
    }
    __syncthreads();
#pragma unroll
    for (int i = 0; i < 16; ++i) {
        const int idx = i * 256 + tid;
        const int d = idx >> 6, fl = idx & 63;
        tl[dst + (i64)d * SEQ + fl] = tile[d][fl];
    }
}

// ---------------------------------------------------------------------------
// loss = mean_h ( 1 / min_i l[h][i] )
// ---------------------------------------------------------------------------
__global__ __launch_bounds__(256)
void loss_kernel(const float* __restrict__ lrow, float* __restrict__ out)
{
    __shared__ float red[4];
    const int tx = threadIdx.x, wave = tx >> 6, lane = tx & 63;
    float acc = 0.f;
    for (int h = 0; h < NHEADS; ++h) {
        float m = 3.0e38f;
#pragma unroll
        for (int k = 0; k < 8; ++k) m = fminf(m, lrow[(i64)h * SEQ + k * 256 + tx]);
#pragma unroll
        for (int o = 32; o > 0; o >>= 1) m = fminf(m, __shfl_xor(m, o));
        if (lane == 0) red[wave] = m;
        __syncthreads();
        if (tx == 0) acc += 1.f / fminf(fminf(red[0], red[1]), fminf(red[2], red[3]));
        __syncthreads();
    }
    if (tx == 0) *out = acc * (1.f / NHEADS);
}

// ---------------------------------------------------------------------------
extern "C" void kernel_launch(void* const* d_in, const int* in_sizes, int n_in,
                              void* d_out, int out_size, void* d_ws, size_t ws_size,
                              hipStream_t stream)
{
    const float* query = (const float*)d_in[0];
    const float* key   = (const float*)d_in[1];
    const float* value = (const float*)d_in[2];
    const float* mask  = (const float*)d_in[3];
    const float* Wq    = (const float*)d_in[4];
    const float* Wke   = (const float*)d_in[5];
    const float* Wkr   = (const float*)d_in[6];
    const float* Wv    = (const float*)d_in[7];
    const float* Wf    = (const float*)d_in[8];
    const float* u_p   = (const float*)d_in[9];
    const float* v_p   = (const float*)d_in[10];

    float* out_final = (float*)d_out;
    float* weights   = out_final + (i64)SEQ * DMODEL;
    float* loss      = weights + (i64)NHEADS * SEQ * SEQ;

    // workspace layout
    char* w = (char*)d_ws;
    u16* in_h = (u16*)w;               w += (i64)4 * IN_E * 2;   // [query][key][value][rel]
    u16* in_l = (u16*)w;               w += (i64)4 * IN_E * 2;
    u16* W_h  = (u16*)w;               w += (i64)5 * W_E * 2;    // [Wq][Wke][Wv][Wkr][Wf]
    u16* W_l  = (u16*)w;               w += (i64)5 * W_E * 2;
    u16* P_h  = (u16*)w;               w += (i64)4 * IN_E * 2;   // [qu][kk][vv][rr]
    u16* P_l  = (u16*)w;               w += (i64)4 * IN_E * 2;
    u16* qv_h = (u16*)w;               w += (i64)IN_E * 2;
    u16* qv_l = (u16*)w;               w += (i64)IN_E * 2;
    u16* vvT_h = (u16*)w;              w += (i64)IN_E * 2;
    u16* vvT_l = (u16*)w;              w += (i64)IN_E * 2;
    u16* o_h  = (u16*)w;               w += (i64)IN_E * 2;
    u16* o_l  = (u16*)w;               w += (i64)IN_E * 2;
    float* lrow = (float*)w;           w += (i64)NHEADS * SEQ * 4;
    float* Opart = (float*)w;          w += (i64)2 * IN_E * 4;

    dim3 blk(256);

    // split inputs + weights
    SplitArgs sa;
    sa.src[0] = query; sa.dh[0] = in_h;           sa.dl[0] = in_l;           sa.n4[0] = IN_E / 4;
    sa.src[1] = key;   sa.dh[1] = in_h + IN_E;    sa.dl[1] = in_l + IN_E;    sa.n4[1] = IN_E / 4;
    sa.src[2] = value; sa.dh[2] = in_h + 2*IN_E;  sa.dl[2] = in_l + 2*IN_E;  sa.n4[2] = IN_E / 4;
    sa.src[3] = Wq;    sa.dh[3] = W_h;            sa.dl[3] = W_l;            sa.n4[3] = W_E / 4;
    sa.src[4] = Wke;   sa.dh[4] = W_h + W_E;      sa.dl[4] = W_l + W_E;      sa.n4[4] = W_E / 4;
    sa.src[5] = Wv;    sa.dh[5] = W_h + 2*W_E;    sa.dl[5] = W_l + 2*W_E;    sa.n4[5] = W_E / 4;
    sa.src[6] = Wkr;   sa.dh[6] = W_h + 3*W_E;    sa.dl[6] = W_l + 3*W_E;    sa.n4[6] = W_E / 4;
    sa.src[7] = Wf;    sa.dh[7] = W_h + 4*W_E;    sa.dl[7] = W_l + 4*W_E;    sa.n4[7] = W_E / 4;
    split_all<<<dim3(2048, 8), blk, 0, stream>>>(sa);
    posenc_split<<<dim3(IN_E / 256), blk, 0, stream>>>(in_h + 3*(i64)IN_E, in_l + 3*(i64)IN_E);

    // projections: z in {q,k,v,r}
    {
        TNArgs p = {};
        p.Ah = in_h; p.Al = in_l; p.Bh = W_h; p.Bl = W_l;
        p.sAz = IN_E; p.sBz = W_E;
        p.O1h = P_h; p.O1l = P_l; p.O2h = qv_h; p.O2l = qv_l;
        p.b1 = u_p; p.b2 = v_p;
        p.K = DMODEL; p.mode = 1;
        mfma_tn128<<<dim3(DMODEL / 128, SEQ / 128, 4), blk, 0, stream>>>(p);
    }

    transpose_vv<<<dim3(SEQ / 64, NHEADS), blk, 0, stream>>>(
        P_h + 2*(i64)IN_E, P_l + 2*(i64)IN_E, vvT_h, vvT_l);

    // fused AC + shifted-BD scores -> raw f32 into weights region
    {
        ScoreArgs p;
        p.quh = P_h;             p.qul = P_l;
        p.kkh = P_h + IN_E;      p.kkl = P_l + IN_E;
        p.qvh = qv_h;            p.qvl = qv_l;
        p.rrh = P_h + 3*(i64)IN_E; p.rrl = P_l + 3*(i64)IN_E;
        p.Cf = weights;
        mfma_score<<<dim3(SEQ / 128, SEQ / 128, NHEADS), blk, 0, stream>>>(p);
    }

    // softmax normalize in place
    softmax_norm<<<dim3(SEQ / 4, NHEADS), blk, 0, stream>>>(weights, mask, lrow);

    // PV split-K into partials, then merge+split
    mfma_pv<<<dim3(2, SEQ / 256, NHEADS), blk, 0, stream>>>(weights, vvT_h, vvT_l, Opart);
    merge_split<<<dim3(IN_E / 4 / 256), blk, 0, stream>>>(Opart, Opart + IN_E, o_h, o_l);

    // final GEMM + GELU
    {
        TNArgs p = {};
        p.Ah = o_h; p.Al = o_l;
        p.Bh = W_h + 4*(i64)W_E; p.Bl = W_l + 4*(i64)W_E;
        p.sAz = 0; p.sBz = 0;
        p.Cf = out_final; p.sCz = 0; p.ldc = DMODEL;
        p.K = DMODEL; p.mode = 2;
        mfma_tn128<<<dim3(DMODEL / 128, SEQ / 128, 1), blk, 0, stream>>>(p);
    }

    loss_kernel<<<dim3(1), blk, 0, stream>>>(lrow, loss);
}